// Round 1
// baseline (897.959 us; speedup 1.0000x reference)
//
#include <hip/hip_runtime.h>
#include <math.h>

#define N_ 4
#define L_ 2048
#define E_ 512
#define H_ 8
#define D_ 64

// 1/sqrt(EMBED) -- reference scales by sqrt(embed_size), not sqrt(head_dim)
#define SCALE 0.044194173824159216f

// ---------------------------------------------------------------------------
// Kernel 1: per-head QKV projection.
// row r = (n*L + l)*H + h ; x = in[(n*L+l)*E + h*D .. +64]
// out[((n*H+h)*L + l)*D + e] = sum_d x[d] * W[e*D+d]    (x @ W^T, torch Linear)
// W accessed with wave-uniform indices -> scalar loads, no LDS needed.
// ---------------------------------------------------------------------------
__device__ __forceinline__ void proj_one(const float4* __restrict__ x4,
                                         const float* __restrict__ W,
                                         float* __restrict__ out)
{
#pragma unroll 2
    for (int e4 = 0; e4 < 16; ++e4) {
        float tmp[4];
#pragma unroll
        for (int c = 0; c < 4; ++c) {
            const int e = e4 * 4 + c;
            float a = 0.f;
#pragma unroll
            for (int d4 = 0; d4 < 16; ++d4) {
                const float4 w = reinterpret_cast<const float4*>(W + e * D_)[d4];
                const float4 xv = x4[d4];
                a += xv.x * w.x;
                a += xv.y * w.y;
                a += xv.z * w.z;
                a += xv.w * w.w;
            }
            tmp[c] = a;
        }
        float4 res = make_float4(tmp[0], tmp[1], tmp[2], tmp[3]);
        reinterpret_cast<float4*>(out)[e4] = res;
    }
}

__global__ __launch_bounds__(256) void qkv_proj_kernel(
    const float* __restrict__ Q, const float* __restrict__ K, const float* __restrict__ V,
    const float* __restrict__ Wq, const float* __restrict__ Wk, const float* __restrict__ Wv,
    float* __restrict__ Qp, float* __restrict__ Kp, float* __restrict__ Vp)
{
    const int r = blockIdx.x * 256 + threadIdx.x;   // 0 .. N*L*H-1
    const int h = r & (H_ - 1);
    const int nl = r >> 3;
    const int n = nl >> 11;          // / L_
    const int l = nl & (L_ - 1);
    const size_t xoff = (size_t)nl * E_ + (size_t)h * D_;
    const size_t ooff = ((size_t)(n * H_ + h) * L_ + l) * D_;

    float4 x4[16];

    // Q
#pragma unroll
    for (int i = 0; i < 16; ++i) x4[i] = reinterpret_cast<const float4*>(Q + xoff)[i];
    proj_one(x4, Wq, Qp + ooff);
    // K
#pragma unroll
    for (int i = 0; i < 16; ++i) x4[i] = reinterpret_cast<const float4*>(K + xoff)[i];
    proj_one(x4, Wk, Kp + ooff);
    // V
#pragma unroll
    for (int i = 0; i < 16; ++i) x4[i] = reinterpret_cast<const float4*>(V + xoff)[i];
    proj_one(x4, Wv, Vp + ooff);
}

// ---------------------------------------------------------------------------
// Kernel 2: flash attention (fp32), one block = 64 q-rows of one (n,h).
// Layouts: Qp/Kp/Vp are [N*H][L][D]. Output AO is [N][L][E] (heads re-merged).
// Block 256 threads: thread -> (qa = tid/8 in 0..31, owns rows qa and qa+32,
//                               sl = tid%8: k-slice in QK, d-slice in PV)
// Online softmax state per q-row (replicated across the 8 lanes of its group).
// Pt rows are written and read only by the same 8-lane group (same wave) ->
// no barrier needed between softmax write and PV read.
// ---------------------------------------------------------------------------
__global__ __launch_bounds__(256) void attn_kernel(
    const float* __restrict__ Qp, const float* __restrict__ Kp, const float* __restrict__ Vp,
    float* __restrict__ AO)
{
    __shared__ float Qt[64][68];
    __shared__ float Kt[64][68];
    __shared__ float Vt[64][68];
    __shared__ float Pt[64][68];

    const int bid = blockIdx.x;
    const int qt = bid & 31;         // 32 q-tiles of 64
    const int nh = bid >> 5;         // 0..31
    const int n = nh >> 3, h = nh & 7;
    const int q0 = qt * 64;
    const int tid = threadIdx.x;

    const float* __restrict__ Qb = Qp + (size_t)nh * L_ * D_;
    const float* __restrict__ Kb = Kp + (size_t)nh * L_ * D_;
    const float* __restrict__ Vb = Vp + (size_t)nh * L_ * D_;

    // stage Q tile (64x64) once
#pragma unroll
    for (int it = 0; it < 4; ++it) {
        const int idx = tid + it * 256;       // 0..1023 float4 units
        const int row = idx >> 4, c4 = idx & 15;
        *reinterpret_cast<float4*>(&Qt[row][c4 * 4]) =
            reinterpret_cast<const float4*>(Qb + (size_t)(q0 + row) * D_)[c4];
    }

    const int qa = tid >> 3;      // 0..31
    const int qb = qa + 32;
    const int sl = tid & 7;

    float m[2]; m[0] = -INFINITY; m[1] = -INFINITY;
    float lsum[2]; lsum[0] = 0.f; lsum[1] = 0.f;
    float o[2][8];
#pragma unroll
    for (int rr = 0; rr < 2; ++rr)
#pragma unroll
        for (int j = 0; j < 8; ++j) o[rr][j] = 0.f;

    for (int kt = 0; kt < L_ / 64; ++kt) {
        __syncthreads();   // previous iteration done with Kt/Vt; also covers Qt on kt=0
        // stage K,V tiles (64x64 each)
#pragma unroll
        for (int it = 0; it < 4; ++it) {
            const int idx = tid + it * 256;
            const int row = idx >> 4, c4 = idx & 15;
            *reinterpret_cast<float4*>(&Kt[row][c4 * 4]) =
                reinterpret_cast<const float4*>(Kb + (size_t)(kt * 64 + row) * D_)[c4];
            *reinterpret_cast<float4*>(&Vt[row][c4 * 4]) =
                reinterpret_cast<const float4*>(Vb + (size_t)(kt * 64 + row) * D_)[c4];
        }
        __syncthreads();

        // ---- QK^T : s[2][8], k = sl + 8j ----
        float s[2][8];
#pragma unroll
        for (int rr = 0; rr < 2; ++rr)
#pragma unroll
            for (int j = 0; j < 8; ++j) s[rr][j] = 0.f;

#pragma unroll
        for (int d4 = 0; d4 < 16; ++d4) {
            const float4 qva = *reinterpret_cast<const float4*>(&Qt[qa][d4 * 4]);
            const float4 qvb = *reinterpret_cast<const float4*>(&Qt[qb][d4 * 4]);
#pragma unroll
            for (int j = 0; j < 8; ++j) {
                const float4 kv = *reinterpret_cast<const float4*>(&Kt[sl + 8 * j][d4 * 4]);
                s[0][j] += qva.x * kv.x + qva.y * kv.y + qva.z * kv.z + qva.w * kv.w;
                s[1][j] += qvb.x * kv.x + qvb.y * kv.y + qvb.z * kv.z + qvb.w * kv.w;
            }
        }

        // ---- online softmax (per q-row, within its 8-lane group) ----
#pragma unroll
        for (int rr = 0; rr < 2; ++rr) {
            const int qrow = (rr == 0) ? qa : qb;
            float tmax = -INFINITY;
#pragma unroll
            for (int j = 0; j < 8; ++j) {
                s[rr][j] *= SCALE;
                tmax = fmaxf(tmax, s[rr][j]);
            }
            tmax = fmaxf(tmax, __shfl_xor(tmax, 1));
            tmax = fmaxf(tmax, __shfl_xor(tmax, 2));
            tmax = fmaxf(tmax, __shfl_xor(tmax, 4));
            const float newm = fmaxf(m[rr], tmax);
            const float corr = __expf(m[rr] - newm);   // 0 on first tile (m = -inf)
            float tsum = 0.f;
#pragma unroll
            for (int j = 0; j < 8; ++j) {
                const float p = __expf(s[rr][j] - newm);
                Pt[qrow][sl + 8 * j] = p;
                tsum += p;
            }
            tsum += __shfl_xor(tsum, 1);
            tsum += __shfl_xor(tsum, 2);
            tsum += __shfl_xor(tsum, 4);
            lsum[rr] = lsum[rr] * corr + tsum;
            m[rr] = newm;
#pragma unroll
            for (int j = 0; j < 8; ++j) o[rr][j] *= corr;
        }

        // ---- PV : d = sl*8 + j ----
#pragma unroll 4
        for (int k = 0; k < 64; ++k) {
            const float pa = Pt[qa][k];
            const float pb = Pt[qb][k];
            const float4 va = *reinterpret_cast<const float4*>(&Vt[k][sl * 8]);
            const float4 vb = *reinterpret_cast<const float4*>(&Vt[k][sl * 8 + 4]);
            float vv[8];
            vv[0] = va.x; vv[1] = va.y; vv[2] = va.z; vv[3] = va.w;
            vv[4] = vb.x; vv[5] = vb.y; vv[6] = vb.z; vv[7] = vb.w;
#pragma unroll
            for (int j = 0; j < 8; ++j) {
                o[0][j] += pa * vv[j];
                o[1][j] += pb * vv[j];
            }
        }
    }

    // epilogue: normalize and write AO[N][L][E]
#pragma unroll
    for (int rr = 0; rr < 2; ++rr) {
        const int qrow = (rr == 0) ? qa : qb;
        const float inv = 1.f / lsum[rr];
        const float4 oa = make_float4(o[rr][0] * inv, o[rr][1] * inv, o[rr][2] * inv, o[rr][3] * inv);
        const float4 ob = make_float4(o[rr][4] * inv, o[rr][5] * inv, o[rr][6] * inv, o[rr][7] * inv);
        const size_t base = ((size_t)n * L_ + (q0 + qrow)) * E_ + (size_t)h * D_ + sl * 8;
        *reinterpret_cast<float4*>(AO + base) = oa;
        *reinterpret_cast<float4*>(AO + base + 4) = ob;
    }
}

// ---------------------------------------------------------------------------
// Kernel 3: output projection  out[m][n] = sum_k AO[m][k]*Wo[n][k] + bo[n]
// M=8192, N=512, K=512.  64x64 tiles, 4x4 register blocking.
// A and W tiles staged TRANSPOSED in LDS ([k][m]/[k][n]) so the inner loop is
// two ds_read_b128 per k.
// ---------------------------------------------------------------------------
__global__ __launch_bounds__(256) void out_proj_kernel(
    const float* __restrict__ AO, const float* __restrict__ Wo,
    const float* __restrict__ bo, float* __restrict__ out)
{
    __shared__ float At[64][68];
    __shared__ float Wt[64][68];

    const int bid = blockIdx.x;
    const int mtile = bid >> 3;      // 0..127
    const int ntile = bid & 7;       // 0..7
    const int m0 = mtile * 64, n0 = ntile * 64;
    const int tid = threadIdx.x;
    const int tm = tid >> 4, tn = tid & 15;

    float acc[4][4];
#pragma unroll
    for (int i = 0; i < 4; ++i)
#pragma unroll
        for (int c = 0; c < 4; ++c) acc[i][c] = 0.f;

    for (int kc = 0; kc < 8; ++kc) {
        const int k0 = kc * 64;
        __syncthreads();
#pragma unroll
        for (int it = 0; it < 4; ++it) {
            const int idx = tid + it * 256;        // 0..1023 float4 units
            const int row = idx >> 4, c4 = idx & 15;
            const float4 a = reinterpret_cast<const float4*>(AO + (size_t)(m0 + row) * E_ + k0)[c4];
            At[c4 * 4 + 0][row] = a.x;
            At[c4 * 4 + 1][row] = a.y;
            At[c4 * 4 + 2][row] = a.z;
            At[c4 * 4 + 3][row] = a.w;
            const float4 w = reinterpret_cast<const float4*>(Wo + (size_t)(n0 + row) * E_ + k0)[c4];
            Wt[c4 * 4 + 0][row] = w.x;
            Wt[c4 * 4 + 1][row] = w.y;
            Wt[c4 * 4 + 2][row] = w.z;
            Wt[c4 * 4 + 3][row] = w.w;
        }
        __syncthreads();

#pragma unroll 8
        for (int kk = 0; kk < 64; ++kk) {
            const float4 a4 = *reinterpret_cast<const float4*>(&At[kk][tm * 4]);
            const float4 w4 = *reinterpret_cast<const float4*>(&Wt[kk][tn * 4]);
            float av[4] = {a4.x, a4.y, a4.z, a4.w};
            float wv[4] = {w4.x, w4.y, w4.z, w4.w};
#pragma unroll
            for (int i = 0; i < 4; ++i)
#pragma unroll
                for (int c = 0; c < 4; ++c) acc[i][c] += av[i] * wv[c];
        }
    }

    const float4 b4 = *reinterpret_cast<const float4*>(bo + n0 + tn * 4);
#pragma unroll
    for (int i = 0; i < 4; ++i) {
        const int mm = m0 + tm * 4 + i;
        const float4 res = make_float4(acc[i][0] + b4.x, acc[i][1] + b4.y,
                                       acc[i][2] + b4.z, acc[i][3] + b4.w);
        *reinterpret_cast<float4*>(out + (size_t)mm * E_ + n0 + tn * 4) = res;
    }
}

// ---------------------------------------------------------------------------
extern "C" void kernel_launch(void* const* d_in, const int* in_sizes, int n_in,
                              void* d_out, int out_size, void* d_ws, size_t ws_size,
                              hipStream_t stream)
{
    const float* Q  = (const float*)d_in[0];
    const float* K  = (const float*)d_in[1];
    const float* V  = (const float*)d_in[2];
    const float* Wq = (const float*)d_in[3];
    const float* Wk = (const float*)d_in[4];
    const float* Wv = (const float*)d_in[5];
    const float* Wo = (const float*)d_in[6];
    const float* bo = (const float*)d_in[7];
    float* out = (float*)d_out;

    float* ws = (float*)d_ws;
    const size_t SZ = (size_t)N_ * H_ * L_ * D_;   // 4,194,304 floats
    float* Qp = ws;
    float* Kp = ws + SZ;
    float* Vp = ws + 2 * SZ;
    float* AO = ws + 3 * SZ;

    qkv_proj_kernel<<<256, 256, 0, stream>>>(Q, K, V, Wq, Wk, Wv, Qp, Kp, Vp);
    attn_kernel<<<N_ * H_ * (L_ / 64), 256, 0, stream>>>(Qp, Kp, Vp, AO);
    out_proj_kernel<<<(8192 / 64) * (E_ / 64), 256, 0, stream>>>(AO, Wo, bo, out);
}

// Round 2
// 279.937 us; speedup vs baseline: 3.2077x; 3.2077x over previous
//
#include <hip/hip_runtime.h>
#include <math.h>

#define N_ 4
#define L_ 2048
#define E_ 512
#define H_ 8
#define D_ 64

// 1/sqrt(EMBED) -- reference scales by sqrt(embed_size), not sqrt(head_dim)
#define SCALE 0.044194173824159216f

typedef short s16x8 __attribute__((ext_vector_type(8)));
typedef float f32x4 __attribute__((ext_vector_type(4)));

__device__ __forceinline__ unsigned short f2bf(float x) {
    unsigned int u = __builtin_bit_cast(unsigned int, x);
    u = (u + 0x7FFFu + ((u >> 16) & 1u)) >> 16;   // RNE
    return (unsigned short)u;
}
__device__ __forceinline__ unsigned int pack2(float lo, float hi) {
    return (unsigned int)f2bf(lo) | ((unsigned int)f2bf(hi) << 16);
}
__device__ __forceinline__ float bflo(unsigned int w) {
    return __builtin_bit_cast(float, w << 16);
}
__device__ __forceinline__ float bfhi(unsigned int w) {
    return __builtin_bit_cast(float, w & 0xFFFF0000u);
}

// ---------------------------------------------------------------------------
// Kernel 1: per-head QKV projection (fp32 compute, bf16 output).
// Qp/Kp: [nh][l][d] bf16 row-major.  Vt: [nh][d][l] bf16 (transposed so the
// attention kernel's PV A-operand (V^T) reads contiguous keys).
// ---------------------------------------------------------------------------
__global__ __launch_bounds__(256) void qkv_proj_kernel(
    const float* __restrict__ Q, const float* __restrict__ K, const float* __restrict__ V,
    const float* __restrict__ Wq, const float* __restrict__ Wk, const float* __restrict__ Wv,
    unsigned short* __restrict__ Qp, unsigned short* __restrict__ Kp,
    unsigned short* __restrict__ Vt)
{
    const int r = blockIdx.x * 256 + threadIdx.x;   // 0 .. N*L*H-1
    const int h = r & 7;
    const int nl = r >> 3;
    const int n = nl >> 11;
    const int l = nl & 2047;
    const int nh = n * 8 + h;
    const size_t xoff = (size_t)nl * E_ + (size_t)h * D_;
    const size_t ooff = ((size_t)nh * L_ + l) * D_;

    float4 x4[16];

    // ---- Q ----
#pragma unroll
    for (int i = 0; i < 16; ++i) x4[i] = reinterpret_cast<const float4*>(Q + xoff)[i];
#pragma unroll 2
    for (int e4 = 0; e4 < 16; ++e4) {
        float tmp[4];
#pragma unroll
        for (int c = 0; c < 4; ++c) {
            const float* Wr = Wq + (e4 * 4 + c) * D_;
            float a = 0.f;
#pragma unroll
            for (int d4 = 0; d4 < 16; ++d4) {
                const float4 w = reinterpret_cast<const float4*>(Wr)[d4];
                a += x4[d4].x * w.x + x4[d4].y * w.y + x4[d4].z * w.z + x4[d4].w * w.w;
            }
            tmp[c] = a;
        }
        uint2 o; o.x = pack2(tmp[0], tmp[1]); o.y = pack2(tmp[2], tmp[3]);
        reinterpret_cast<uint2*>(Qp + ooff)[e4] = o;
    }

    // ---- K ----
#pragma unroll
    for (int i = 0; i < 16; ++i) x4[i] = reinterpret_cast<const float4*>(K + xoff)[i];
#pragma unroll 2
    for (int e4 = 0; e4 < 16; ++e4) {
        float tmp[4];
#pragma unroll
        for (int c = 0; c < 4; ++c) {
            const float* Wr = Wk + (e4 * 4 + c) * D_;
            float a = 0.f;
#pragma unroll
            for (int d4 = 0; d4 < 16; ++d4) {
                const float4 w = reinterpret_cast<const float4*>(Wr)[d4];
                a += x4[d4].x * w.x + x4[d4].y * w.y + x4[d4].z * w.z + x4[d4].w * w.w;
            }
            tmp[c] = a;
        }
        uint2 o; o.x = pack2(tmp[0], tmp[1]); o.y = pack2(tmp[2], tmp[3]);
        reinterpret_cast<uint2*>(Kp + ooff)[e4] = o;
    }

    // ---- V (transposed store) ----
#pragma unroll
    for (int i = 0; i < 16; ++i) x4[i] = reinterpret_cast<const float4*>(V + xoff)[i];
#pragma unroll 2
    for (int e4 = 0; e4 < 16; ++e4) {
#pragma unroll
        for (int c = 0; c < 4; ++c) {
            const float* Wr = Wv + (e4 * 4 + c) * D_;
            float a = 0.f;
#pragma unroll
            for (int d4 = 0; d4 < 16; ++d4) {
                const float4 w = reinterpret_cast<const float4*>(Wr)[d4];
                a += x4[d4].x * w.x + x4[d4].y * w.y + x4[d4].z * w.z + x4[d4].w * w.w;
            }
            Vt[((size_t)nh * D_ + (e4 * 4 + c)) * L_ + l] = f2bf(a);
        }
    }
}

// ---------------------------------------------------------------------------
// Kernel 2: bf16 MFMA flash attention.
// Block = 256 threads (4 waves), QBLK=64 (16 q-rows per wave), KVBLK=64, D=64.
// Swapped orientation: St = K·Q^T (mfma A=K, B=Q^T) and Ot = V^T·P^T
// (mfma A=V^T, B=P^T) so softmax state and O-rescale are lane-local (q=lane&15).
// All LDS tiles XOR-swizzled: ushort idx ^= (row&7)<<3 (16B granules).
// ---------------------------------------------------------------------------
__global__ __launch_bounds__(256) void attn_kernel(
    const unsigned short* __restrict__ Qp, const unsigned short* __restrict__ Kp,
    const unsigned short* __restrict__ Vt, unsigned short* __restrict__ AO)
{
    __shared__ __align__(16) unsigned short Qlds[64 * 64];
    __shared__ __align__(16) unsigned short Klds[64 * 64];
    __shared__ __align__(16) unsigned short Vlds[64 * 64];
    __shared__ __align__(16) unsigned short Plds[4 * 16 * 64];

    const int tid = threadIdx.x;
    const int bid = blockIdx.x;
    const int qt = bid & 31;        // q-tile
    const int nh = bid >> 5;        // 0..31
    const int n = nh >> 3, h = nh & 7;
    const int q0 = qt * 64;
    const int wave = tid >> 6;
    const int lane = tid & 63;
    const int ql = lane & 15;       // q-local (col index) for this wave
    const int g  = lane >> 4;       // k-slot group

    const unsigned short* __restrict__ Qb = Qp + (size_t)nh * L_ * D_;
    const unsigned short* __restrict__ Kb = Kp + (size_t)nh * L_ * D_;
    const unsigned short* __restrict__ Vb = Vt + (size_t)nh * D_ * L_;

    // ---- stage Q tile (64 rows x 64 d), swizzled ----
#pragma unroll
    for (int it = 0; it < 2; ++it) {
        const int idx = tid + it * 256;          // 0..511, 16B units
        const int row = idx >> 3, c8 = idx & 7;
        const int4 v = *reinterpret_cast<const int4*>(Qb + (size_t)(q0 + row) * D_ + c8 * 8);
        *reinterpret_cast<int4*>(&Qlds[(row * 64 + c8 * 8) ^ ((row & 7) << 3)]) = v;
    }
    __syncthreads();

    // hoist Q B-frags: B[k=d][col=q], q = wave*16+ql, d = ks*32 + g*8 + j
    const int qrow = wave * 16 + ql;
    s16x8 qfrag[2];
#pragma unroll
    for (int ks = 0; ks < 2; ++ks)
        qfrag[ks] = *reinterpret_cast<const s16x8*>(
            &Qlds[(qrow * 64 + ks * 32 + g * 8) ^ ((qrow & 7) << 3)]);

    unsigned short* __restrict__ Pl = Plds + wave * 16 * 64;

    float m_ = -INFINITY;
    float lsum = 0.f;
    f32x4 ot[4];
#pragma unroll
    for (int t = 0; t < 4; ++t)
#pragma unroll
        for (int i = 0; i < 4; ++i) ot[t][i] = 0.f;

    for (int kt = 0; kt < L_ / 64; ++kt) {
        __syncthreads();
        // ---- stage K tile [key][d] and V^T tile [d][key], swizzled ----
#pragma unroll
        for (int it = 0; it < 2; ++it) {
            const int idx = tid + it * 256;
            const int row = idx >> 3, c8 = idx & 7;
            const int4 kv = *reinterpret_cast<const int4*>(
                Kb + (size_t)(kt * 64 + row) * D_ + c8 * 8);
            *reinterpret_cast<int4*>(&Klds[(row * 64 + c8 * 8) ^ ((row & 7) << 3)]) = kv;
            const int4 vv = *reinterpret_cast<const int4*>(
                Vb + (size_t)row * L_ + kt * 64 + c8 * 8);
            *reinterpret_cast<int4*>(&Vlds[(row * 64 + c8 * 8) ^ ((row & 7) << 3)]) = vv;
        }
        __syncthreads();

        // ---- St = K·Q^T : st[kv][r] = S[key=kv*16+g*4+r][q=wave*16+ql] ----
        f32x4 st[4];
#pragma unroll
        for (int kv = 0; kv < 4; ++kv) {
#pragma unroll
            for (int i = 0; i < 4; ++i) st[kv][i] = 0.f;
#pragma unroll
            for (int ks = 0; ks < 2; ++ks) {
                const int krow = kv * 16 + ql;
                const s16x8 kf = *reinterpret_cast<const s16x8*>(
                    &Klds[(krow * 64 + ks * 32 + g * 8) ^ ((krow & 7) << 3)]);
                st[kv] = __builtin_amdgcn_mfma_f32_16x16x32_bf16(kf, qfrag[ks], st[kv], 0, 0, 0);
            }
        }

        // ---- online softmax (q = ql, lane-local state) ----
        float ps[16];
        float tmax = -INFINITY;
#pragma unroll
        for (int kv = 0; kv < 4; ++kv)
#pragma unroll
            for (int rr = 0; rr < 4; ++rr) {
                const float v = st[kv][rr] * SCALE;
                ps[kv * 4 + rr] = v;
                tmax = fmaxf(tmax, v);
            }
        tmax = fmaxf(tmax, __shfl_xor(tmax, 16));
        tmax = fmaxf(tmax, __shfl_xor(tmax, 32));
        const float newm = fmaxf(m_, tmax);
        const float corr = __expf(m_ - newm);     // 0 on first tile
        float tsum = 0.f;
#pragma unroll
        for (int i = 0; i < 16; ++i) {
            ps[i] = __expf(ps[i] - newm);
            tsum += ps[i];
        }
        tsum += __shfl_xor(tsum, 16);
        tsum += __shfl_xor(tsum, 32);
        lsum = lsum * corr + tsum;
        m_ = newm;
#pragma unroll
        for (int t = 0; t < 4; ++t) ot[t] *= corr;

        // ---- P (bf16) -> per-wave LDS [q][key], swizzled; same-wave use ----
#pragma unroll
        for (int kv = 0; kv < 4; ++kv) {
            uint2 pw;
            pw.x = pack2(ps[kv * 4 + 0], ps[kv * 4 + 1]);
            pw.y = pack2(ps[kv * 4 + 2], ps[kv * 4 + 3]);
            *reinterpret_cast<uint2*>(
                &Pl[(ql * 64 + kv * 16 + g * 4) ^ ((ql & 7) << 3)]) = pw;
        }

        // ---- Ot += V^T·P^T : A=V^T rows d, B=P^T cols q ----
        s16x8 pf[2];
#pragma unroll
        for (int ks = 0; ks < 2; ++ks)
            pf[ks] = *reinterpret_cast<const s16x8*>(
                &Pl[(ql * 64 + ks * 32 + g * 8) ^ ((ql & 7) << 3)]);
#pragma unroll
        for (int dt = 0; dt < 4; ++dt) {
            const int drow = dt * 16 + ql;
#pragma unroll
            for (int ks = 0; ks < 2; ++ks) {
                const s16x8 vf = *reinterpret_cast<const s16x8*>(
                    &Vlds[(drow * 64 + ks * 32 + g * 8) ^ ((drow & 7) << 3)]);
                ot[dt] = __builtin_amdgcn_mfma_f32_16x16x32_bf16(vf, pf[ks], ot[dt], 0, 0, 0);
            }
        }
    }

    // ---- epilogue: lane holds Ot[d=dt*16+g*4+r][q=ql]; write AO bf16 ----
    const float inv = 1.f / lsum;
    const int lq = q0 + wave * 16 + ql;
#pragma unroll
    for (int dt = 0; dt < 4; ++dt) {
        uint2 o;
        o.x = pack2(ot[dt][0] * inv, ot[dt][1] * inv);
        o.y = pack2(ot[dt][2] * inv, ot[dt][3] * inv);
        const size_t elem = ((size_t)n * L_ + lq) * E_ + h * D_ + dt * 16 + g * 4;
        *reinterpret_cast<uint2*>(AO + elem) = o;
    }
}

// ---------------------------------------------------------------------------
// Kernel 3: output projection  out[m][n] = sum_k AO[m][k]*Wo[n][k] + bo[n]
// M=8192, N=512, K=512. AO is bf16; Wo fp32; fp32 accumulate.
// ---------------------------------------------------------------------------
__global__ __launch_bounds__(256) void out_proj_kernel(
    const unsigned short* __restrict__ AO, const float* __restrict__ Wo,
    const float* __restrict__ bo, float* __restrict__ out)
{
    __shared__ float At[64][68];
    __shared__ float Wt[64][68];

    const int bid = blockIdx.x;
    const int mtile = bid >> 3;
    const int ntile = bid & 7;
    const int m0 = mtile * 64, n0 = ntile * 64;
    const int tid = threadIdx.x;
    const int tm = tid >> 4, tn = tid & 15;

    float acc[4][4];
#pragma unroll
    for (int i = 0; i < 4; ++i)
#pragma unroll
        for (int c = 0; c < 4; ++c) acc[i][c] = 0.f;

    for (int kc = 0; kc < 8; ++kc) {
        const int k0 = kc * 64;
        __syncthreads();
        // A tile from bf16 AO (transposed into LDS)
#pragma unroll
        for (int it = 0; it < 2; ++it) {
            const int idx = tid + it * 256;        // 0..511, 8 elems each
            const int row = idx >> 3, c8 = idx & 7;
            const int4 raw = *reinterpret_cast<const int4*>(
                AO + (size_t)(m0 + row) * E_ + k0 + c8 * 8);
            const unsigned int w0 = (unsigned int)raw.x, w1 = (unsigned int)raw.y;
            const unsigned int w2 = (unsigned int)raw.z, w3 = (unsigned int)raw.w;
            At[c8 * 8 + 0][row] = bflo(w0);
            At[c8 * 8 + 1][row] = bfhi(w0);
            At[c8 * 8 + 2][row] = bflo(w1);
            At[c8 * 8 + 3][row] = bfhi(w1);
            At[c8 * 8 + 4][row] = bflo(w2);
            At[c8 * 8 + 5][row] = bfhi(w2);
            At[c8 * 8 + 6][row] = bflo(w3);
            At[c8 * 8 + 7][row] = bfhi(w3);
        }
        // W tile (fp32)
#pragma unroll
        for (int it = 0; it < 4; ++it) {
            const int idx = tid + it * 256;        // 0..1023 float4 units
            const int row = idx >> 4, c4 = idx & 15;
            const float4 w = reinterpret_cast<const float4*>(Wo + (size_t)(n0 + row) * E_ + k0)[c4];
            Wt[c4 * 4 + 0][row] = w.x;
            Wt[c4 * 4 + 1][row] = w.y;
            Wt[c4 * 4 + 2][row] = w.z;
            Wt[c4 * 4 + 3][row] = w.w;
        }
        __syncthreads();

#pragma unroll 8
        for (int kk = 0; kk < 64; ++kk) {
            const float4 a4 = *reinterpret_cast<const float4*>(&At[kk][tm * 4]);
            const float4 w4 = *reinterpret_cast<const float4*>(&Wt[kk][tn * 4]);
            float av[4] = {a4.x, a4.y, a4.z, a4.w};
            float wv[4] = {w4.x, w4.y, w4.z, w4.w};
#pragma unroll
            for (int i = 0; i < 4; ++i)
#pragma unroll
                for (int c = 0; c < 4; ++c) acc[i][c] += av[i] * wv[c];
        }
    }

    const float4 b4 = *reinterpret_cast<const float4*>(bo + n0 + tn * 4);
#pragma unroll
    for (int i = 0; i < 4; ++i) {
        const int mm = m0 + tm * 4 + i;
        const float4 res = make_float4(acc[i][0] + b4.x, acc[i][1] + b4.y,
                                       acc[i][2] + b4.z, acc[i][3] + b4.w);
        *reinterpret_cast<float4*>(out + (size_t)mm * E_ + n0 + tn * 4) = res;
    }
}

// ---------------------------------------------------------------------------
extern "C" void kernel_launch(void* const* d_in, const int* in_sizes, int n_in,
                              void* d_out, int out_size, void* d_ws, size_t ws_size,
                              hipStream_t stream)
{
    const float* Q  = (const float*)d_in[0];
    const float* K  = (const float*)d_in[1];
    const float* V  = (const float*)d_in[2];
    const float* Wq = (const float*)d_in[3];
    const float* Wk = (const float*)d_in[4];
    const float* Wv = (const float*)d_in[5];
    const float* Wo = (const float*)d_in[6];
    const float* bo = (const float*)d_in[7];
    float* out = (float*)d_out;

    unsigned short* ws = (unsigned short*)d_ws;
    const size_t SZ = (size_t)N_ * H_ * L_ * D_;   // 4,194,304 elems
    unsigned short* Qp = ws;
    unsigned short* Kp = ws + SZ;
    unsigned short* Vt = ws + 2 * SZ;
    unsigned short* AO = ws + 3 * SZ;

    qkv_proj_kernel<<<256, 256, 0, stream>>>(Q, K, V, Wq, Wk, Wv, Qp, Kp, Vt);
    attn_kernel<<<N_ * H_ * (L_ / 64), 256, 0, stream>>>(Qp, Kp, Vt, AO);
    out_proj_kernel<<<(8192 / 64) * (E_ / 64), 256, 0, stream>>>(AO, Wo, bo, out);
}

// Round 3
// 194.299 us; speedup vs baseline: 4.6215x; 1.4408x over previous
//
#include <hip/hip_runtime.h>
#include <math.h>

#define N_ 4
#define L_ 2048
#define E_ 512
#define H_ 8
#define D_ 64

// 1/sqrt(EMBED) -- reference scales by sqrt(embed_size), not sqrt(head_dim)
#define SCALE 0.044194173824159216f

typedef short s16x8 __attribute__((ext_vector_type(8)));
typedef float f32x4 __attribute__((ext_vector_type(4)));

__device__ __forceinline__ unsigned short f2bf(float x) {
    unsigned int u = __builtin_bit_cast(unsigned int, x);
    u = (u + 0x7FFFu + ((u >> 16) & 1u)) >> 16;   // RNE
    return (unsigned short)u;
}
__device__ __forceinline__ unsigned int pack2(float lo, float hi) {
    return (unsigned int)f2bf(lo) | ((unsigned int)f2bf(hi) << 16);
}
__device__ __forceinline__ float bflo(unsigned int w) {
    return __builtin_bit_cast(float, w << 16);
}
__device__ __forceinline__ float bfhi(unsigned int w) {
    return __builtin_bit_cast(float, w & 0xFFFF0000u);
}

// ---------------------------------------------------------------------------
// Kernel 1: per-head QKV projection (fp32 compute, bf16 output).
// Grid: (l-tile 0..31, nh 0..31, matrix 0..2). Block 256.
// Stage X tile (64 rows x 64 d) + W (64 e x 64 d) fp32 in LDS; each thread
// computes rows {rp, rp+32} x 8 outputs; results restaged via bf16 LDS tile
// so global stores are fully coalesced for both row-major (Q/K: [nh][l][d])
// and transposed (V: [nh][d][l]) layouts.
// ---------------------------------------------------------------------------
__global__ __launch_bounds__(256) void qkv_proj_kernel(
    const float* __restrict__ Q, const float* __restrict__ K, const float* __restrict__ V,
    const float* __restrict__ Wq, const float* __restrict__ Wk, const float* __restrict__ Wv,
    unsigned short* __restrict__ Qp, unsigned short* __restrict__ Kp,
    unsigned short* __restrict__ Vt)
{
    __shared__ float Xl[64][68];
    __shared__ float Wl[64][68];
    __shared__ __align__(16) unsigned short Yl[64][72];   // 144B rows: 16B-aligned

    const int tid = threadIdx.x;
    const int lt = blockIdx.x;       // l-tile
    const int nh = blockIdx.y;       // 0..31
    const int m  = blockIdx.z;       // 0:Q 1:K 2:V
    const int n = nh >> 3, h = nh & 7;
    const int l0 = lt * 64;

    const float* __restrict__ in = (m == 0) ? Q : (m == 1) ? K : V;
    const float* __restrict__ W  = (m == 0) ? Wq : (m == 1) ? Wk : Wv;

    // ---- stage X (64x64) and W (64x64), coalesced 256B-per-row loads ----
#pragma unroll
    for (int it = 0; it < 4; ++it) {
        const int idx = tid + it * 256;          // 0..1023 float4 units
        const int r = idx >> 4, c4 = idx & 15;
        *reinterpret_cast<float4*>(&Xl[r][c4 * 4]) =
            *reinterpret_cast<const float4*>(in + (size_t)(n * L_ + l0 + r) * E_ + h * D_ + c4 * 4);
        *reinterpret_cast<float4*>(&Wl[r][c4 * 4]) =
            *reinterpret_cast<const float4*>(W + (size_t)r * D_ + c4 * 4);
    }
    __syncthreads();

    const int rp = tid & 31;        // rows rp and rp+32
    const int eg = tid >> 5;        // output group: e = eg*8 + i
    float acc[2][8];
#pragma unroll
    for (int rr = 0; rr < 2; ++rr)
#pragma unroll
        for (int i = 0; i < 8; ++i) acc[rr][i] = 0.f;

#pragma unroll 4
    for (int d4 = 0; d4 < 16; ++d4) {
        const float4 xa = *reinterpret_cast<const float4*>(&Xl[rp][d4 * 4]);
        const float4 xb = *reinterpret_cast<const float4*>(&Xl[rp + 32][d4 * 4]);
#pragma unroll
        for (int i = 0; i < 8; ++i) {
            const float4 w = *reinterpret_cast<const float4*>(&Wl[eg * 8 + i][d4 * 4]);
            acc[0][i] += xa.x * w.x + xa.y * w.y + xa.z * w.z + xa.w * w.w;
            acc[1][i] += xb.x * w.x + xb.y * w.y + xb.z * w.z + xb.w * w.w;
        }
    }

    // ---- restage results as bf16 in Yl ----
    if (m < 2) {
        // Yl[row l][e]
        uint4 pa, pb;
        pa.x = pack2(acc[0][0], acc[0][1]); pa.y = pack2(acc[0][2], acc[0][3]);
        pa.z = pack2(acc[0][4], acc[0][5]); pa.w = pack2(acc[0][6], acc[0][7]);
        pb.x = pack2(acc[1][0], acc[1][1]); pb.y = pack2(acc[1][2], acc[1][3]);
        pb.z = pack2(acc[1][4], acc[1][5]); pb.w = pack2(acc[1][6], acc[1][7]);
        *reinterpret_cast<uint4*>(&Yl[rp][eg * 8]) = pa;
        *reinterpret_cast<uint4*>(&Yl[rp + 32][eg * 8]) = pb;
    } else {
        // Yl[e][row l]  (transposed)
#pragma unroll
        for (int i = 0; i < 8; ++i) {
            Yl[eg * 8 + i][rp] = f2bf(acc[0][i]);
            Yl[eg * 8 + i][rp + 32] = f2bf(acc[1][i]);
        }
    }
    __syncthreads();

    // ---- coalesced store: thread -> 32B (16 bf16) ----
    const int orow = tid >> 2;           // 0..63
    const int oc = (tid & 3) * 16;       // 0,16,32,48
    const uint4 v0 = *reinterpret_cast<const uint4*>(&Yl[orow][oc]);
    const uint4 v1 = *reinterpret_cast<const uint4*>(&Yl[orow][oc + 8]);
    unsigned short* dst;
    if (m == 0)      dst = Qp + ((size_t)nh * L_ + l0 + orow) * D_ + oc;
    else if (m == 1) dst = Kp + ((size_t)nh * L_ + l0 + orow) * D_ + oc;
    else             dst = Vt + ((size_t)nh * D_ + orow) * L_ + l0 + oc;
    *reinterpret_cast<uint4*>(dst) = v0;
    *reinterpret_cast<uint4*>(dst + 8) = v1;
}

// ---------------------------------------------------------------------------
// Kernel 2: bf16 MFMA flash attention.
// Block = 256 threads (4 waves), QBLK=64 (16 q-rows per wave), KVBLK=64, D=64.
// Swapped orientation: St = K·Q^T (mfma A=K, B=Q^T) and Ot = V^T·P^T
// (mfma A=V^T, B=P^T) so softmax state and O-rescale are lane-local (q=lane&15).
// All LDS tiles XOR-swizzled: ushort idx ^= (row&7)<<3 (16B granules).
// ---------------------------------------------------------------------------
__global__ __launch_bounds__(256) void attn_kernel(
    const unsigned short* __restrict__ Qp, const unsigned short* __restrict__ Kp,
    const unsigned short* __restrict__ Vt, unsigned short* __restrict__ AO)
{
    __shared__ __align__(16) unsigned short Qlds[64 * 64];
    __shared__ __align__(16) unsigned short Klds[64 * 64];
    __shared__ __align__(16) unsigned short Vlds[64 * 64];
    __shared__ __align__(16) unsigned short Plds[4 * 16 * 64];

    const int tid = threadIdx.x;
    const int bid = blockIdx.x;
    const int qt = bid & 31;        // q-tile
    const int nh = bid >> 5;        // 0..31
    const int n = nh >> 3, h = nh & 7;
    const int q0 = qt * 64;
    const int wave = tid >> 6;
    const int lane = tid & 63;
    const int ql = lane & 15;       // q-local (col index) for this wave
    const int g  = lane >> 4;       // k-slot group

    const unsigned short* __restrict__ Qb = Qp + (size_t)nh * L_ * D_;
    const unsigned short* __restrict__ Kb = Kp + (size_t)nh * L_ * D_;
    const unsigned short* __restrict__ Vb = Vt + (size_t)nh * D_ * L_;

    // ---- stage Q tile (64 rows x 64 d), swizzled ----
#pragma unroll
    for (int it = 0; it < 2; ++it) {
        const int idx = tid + it * 256;          // 0..511, 16B units
        const int row = idx >> 3, c8 = idx & 7;
        const int4 v = *reinterpret_cast<const int4*>(Qb + (size_t)(q0 + row) * D_ + c8 * 8);
        *reinterpret_cast<int4*>(&Qlds[(row * 64 + c8 * 8) ^ ((row & 7) << 3)]) = v;
    }
    __syncthreads();

    // hoist Q B-frags: B[k=d][col=q], q = wave*16+ql, d = ks*32 + g*8 + j
    const int qrow = wave * 16 + ql;
    s16x8 qfrag[2];
#pragma unroll
    for (int ks = 0; ks < 2; ++ks)
        qfrag[ks] = *reinterpret_cast<const s16x8*>(
            &Qlds[(qrow * 64 + ks * 32 + g * 8) ^ ((qrow & 7) << 3)]);

    unsigned short* __restrict__ Pl = Plds + wave * 16 * 64;

    float m_ = -INFINITY;
    float lsum = 0.f;
    f32x4 ot[4];
#pragma unroll
    for (int t = 0; t < 4; ++t)
#pragma unroll
        for (int i = 0; i < 4; ++i) ot[t][i] = 0.f;

    for (int kt = 0; kt < L_ / 64; ++kt) {
        __syncthreads();
        // ---- stage K tile [key][d] and V^T tile [d][key], swizzled ----
#pragma unroll
        for (int it = 0; it < 2; ++it) {
            const int idx = tid + it * 256;
            const int row = idx >> 3, c8 = idx & 7;
            const int4 kv = *reinterpret_cast<const int4*>(
                Kb + (size_t)(kt * 64 + row) * D_ + c8 * 8);
            *reinterpret_cast<int4*>(&Klds[(row * 64 + c8 * 8) ^ ((row & 7) << 3)]) = kv;
            const int4 vv = *reinterpret_cast<const int4*>(
                Vb + (size_t)row * L_ + kt * 64 + c8 * 8);
            *reinterpret_cast<int4*>(&Vlds[(row * 64 + c8 * 8) ^ ((row & 7) << 3)]) = vv;
        }
        __syncthreads();

        // ---- St = K·Q^T : st[kv][r] = S[key=kv*16+g*4+r][q=wave*16+ql] ----
        f32x4 st[4];
#pragma unroll
        for (int kv = 0; kv < 4; ++kv) {
#pragma unroll
            for (int i = 0; i < 4; ++i) st[kv][i] = 0.f;
#pragma unroll
            for (int ks = 0; ks < 2; ++ks) {
                const int krow = kv * 16 + ql;
                const s16x8 kf = *reinterpret_cast<const s16x8*>(
                    &Klds[(krow * 64 + ks * 32 + g * 8) ^ ((krow & 7) << 3)]);
                st[kv] = __builtin_amdgcn_mfma_f32_16x16x32_bf16(kf, qfrag[ks], st[kv], 0, 0, 0);
            }
        }

        // ---- online softmax (q = ql, lane-local state) ----
        float ps[16];
        float tmax = -INFINITY;
#pragma unroll
        for (int kv = 0; kv < 4; ++kv)
#pragma unroll
            for (int rr = 0; rr < 4; ++rr) {
                const float v = st[kv][rr] * SCALE;
                ps[kv * 4 + rr] = v;
                tmax = fmaxf(tmax, v);
            }
        tmax = fmaxf(tmax, __shfl_xor(tmax, 16));
        tmax = fmaxf(tmax, __shfl_xor(tmax, 32));
        const float newm = fmaxf(m_, tmax);
        const float corr = __expf(m_ - newm);     // 0 on first tile
        float tsum = 0.f;
#pragma unroll
        for (int i = 0; i < 16; ++i) {
            ps[i] = __expf(ps[i] - newm);
            tsum += ps[i];
        }
        tsum += __shfl_xor(tsum, 16);
        tsum += __shfl_xor(tsum, 32);
        lsum = lsum * corr + tsum;
        m_ = newm;
#pragma unroll
        for (int t = 0; t < 4; ++t) ot[t] *= corr;

        // ---- P (bf16) -> per-wave LDS [q][key], swizzled; same-wave use ----
#pragma unroll
        for (int kv = 0; kv < 4; ++kv) {
            uint2 pw;
            pw.x = pack2(ps[kv * 4 + 0], ps[kv * 4 + 1]);
            pw.y = pack2(ps[kv * 4 + 2], ps[kv * 4 + 3]);
            *reinterpret_cast<uint2*>(
                &Pl[(ql * 64 + kv * 16 + g * 4) ^ ((ql & 7) << 3)]) = pw;
        }

        // ---- Ot += V^T·P^T : A=V^T rows d, B=P^T cols q ----
        s16x8 pf[2];
#pragma unroll
        for (int ks = 0; ks < 2; ++ks)
            pf[ks] = *reinterpret_cast<const s16x8*>(
                &Pl[(ql * 64 + ks * 32 + g * 8) ^ ((ql & 7) << 3)]);
#pragma unroll
        for (int dt = 0; dt < 4; ++dt) {
            const int drow = dt * 16 + ql;
#pragma unroll
            for (int ks = 0; ks < 2; ++ks) {
                const s16x8 vf = *reinterpret_cast<const s16x8*>(
                    &Vlds[(drow * 64 + ks * 32 + g * 8) ^ ((drow & 7) << 3)]);
                ot[dt] = __builtin_amdgcn_mfma_f32_16x16x32_bf16(vf, pf[ks], ot[dt], 0, 0, 0);
            }
        }
    }

    // ---- epilogue: lane holds Ot[d=dt*16+g*4+r][q=ql]; write AO bf16 ----
    const float inv = 1.f / lsum;
    const int lq = q0 + wave * 16 + ql;
#pragma unroll
    for (int dt = 0; dt < 4; ++dt) {
        uint2 o;
        o.x = pack2(ot[dt][0] * inv, ot[dt][1] * inv);
        o.y = pack2(ot[dt][2] * inv, ot[dt][3] * inv);
        const size_t elem = ((size_t)n * L_ + lq) * E_ + h * D_ + dt * 16 + g * 4;
        *reinterpret_cast<uint2*>(AO + elem) = o;
    }
}

// ---------------------------------------------------------------------------
// Kernel 3: output projection  out[m][n] = sum_k AO[m][k]*Wo[n][k] + bo[n]
// M=8192, N=512, K=512. AO is bf16; Wo fp32; fp32 accumulate.
// ---------------------------------------------------------------------------
__global__ __launch_bounds__(256) void out_proj_kernel(
    const unsigned short* __restrict__ AO, const float* __restrict__ Wo,
    const float* __restrict__ bo, float* __restrict__ out)
{
    __shared__ float At[64][68];
    __shared__ float Wt[64][68];

    const int bid = blockIdx.x;
    const int mtile = bid >> 3;
    const int ntile = bid & 7;
    const int m0 = mtile * 64, n0 = ntile * 64;
    const int tid = threadIdx.x;
    const int tm = tid >> 4, tn = tid & 15;

    float acc[4][4];
#pragma unroll
    for (int i = 0; i < 4; ++i)
#pragma unroll
        for (int c = 0; c < 4; ++c) acc[i][c] = 0.f;

    for (int kc = 0; kc < 8; ++kc) {
        const int k0 = kc * 64;
        __syncthreads();
        // A tile from bf16 AO (transposed into LDS)
#pragma unroll
        for (int it = 0; it < 2; ++it) {
            const int idx = tid + it * 256;        // 0..511, 8 elems each
            const int row = idx >> 3, c8 = idx & 7;
            const int4 raw = *reinterpret_cast<const int4*>(
                AO + (size_t)(m0 + row) * E_ + k0 + c8 * 8);
            const unsigned int w0 = (unsigned int)raw.x, w1 = (unsigned int)raw.y;
            const unsigned int w2 = (unsigned int)raw.z, w3 = (unsigned int)raw.w;
            At[c8 * 8 + 0][row] = bflo(w0);
            At[c8 * 8 + 1][row] = bfhi(w0);
            At[c8 * 8 + 2][row] = bflo(w1);
            At[c8 * 8 + 3][row] = bfhi(w1);
            At[c8 * 8 + 4][row] = bflo(w2);
            At[c8 * 8 + 5][row] = bfhi(w2);
            At[c8 * 8 + 6][row] = bflo(w3);
            At[c8 * 8 + 7][row] = bfhi(w3);
        }
        // W tile (fp32)
#pragma unroll
        for (int it = 0; it < 4; ++it) {
            const int idx = tid + it * 256;        // 0..1023 float4 units
            const int row = idx >> 4, c4 = idx & 15;
            const float4 w = reinterpret_cast<const float4*>(Wo + (size_t)(n0 + row) * E_ + k0)[c4];
            Wt[c4 * 4 + 0][row] = w.x;
            Wt[c4 * 4 + 1][row] = w.y;
            Wt[c4 * 4 + 2][row] = w.z;
            Wt[c4 * 4 + 3][row] = w.w;
        }
        __syncthreads();

#pragma unroll 8
        for (int kk = 0; kk < 64; ++kk) {
            const float4 a4 = *reinterpret_cast<const float4*>(&At[kk][tm * 4]);
            const float4 w4 = *reinterpret_cast<const float4*>(&Wt[kk][tn * 4]);
            float av[4] = {a4.x, a4.y, a4.z, a4.w};
            float wv[4] = {w4.x, w4.y, w4.z, w4.w};
#pragma unroll
            for (int i = 0; i < 4; ++i)
#pragma unroll
                for (int c = 0; c < 4; ++c) acc[i][c] += av[i] * wv[c];
        }
    }

    const float4 b4 = *reinterpret_cast<const float4*>(bo + n0 + tn * 4);
#pragma unroll
    for (int i = 0; i < 4; ++i) {
        const int mm = m0 + tm * 4 + i;
        const float4 res = make_float4(acc[i][0] + b4.x, acc[i][1] + b4.y,
                                       acc[i][2] + b4.z, acc[i][3] + b4.w);
        *reinterpret_cast<float4*>(out + (size_t)mm * E_ + n0 + tn * 4) = res;
    }
}

// ---------------------------------------------------------------------------
extern "C" void kernel_launch(void* const* d_in, const int* in_sizes, int n_in,
                              void* d_out, int out_size, void* d_ws, size_t ws_size,
                              hipStream_t stream)
{
    const float* Q  = (const float*)d_in[0];
    const float* K  = (const float*)d_in[1];
    const float* V  = (const float*)d_in[2];
    const float* Wq = (const float*)d_in[3];
    const float* Wk = (const float*)d_in[4];
    const float* Wv = (const float*)d_in[5];
    const float* Wo = (const float*)d_in[6];
    const float* bo = (const float*)d_in[7];
    float* out = (float*)d_out;

    unsigned short* ws = (unsigned short*)d_ws;
    const size_t SZ = (size_t)N_ * H_ * L_ * D_;   // 4,194,304 elems
    unsigned short* Qp = ws;
    unsigned short* Kp = ws + SZ;
    unsigned short* Vt = ws + 2 * SZ;
    unsigned short* AO = ws + 3 * SZ;

    qkv_proj_kernel<<<dim3(32, 32, 3), 256, 0, stream>>>(Q, K, V, Wq, Wk, Wv, Qp, Kp, Vt);
    attn_kernel<<<N_ * H_ * (L_ / 64), 256, 0, stream>>>(Qp, Kp, Vt, AO);
    out_proj_kernel<<<(8192 / 64) * (E_ / 64), 256, 0, stream>>>(AO, Wo, bo, out);
}

// Round 4
// 127.745 us; speedup vs baseline: 7.0293x; 1.5210x over previous
//
#include <hip/hip_runtime.h>
#include <math.h>

#define N_ 4
#define L_ 2048
#define E_ 512
#define H_ 8
#define D_ 64

// SCALE = 1/sqrt(512) (reference scales by sqrt(embed_size));
// QSCALE = SCALE * log2(e): scores come out of QK^T in log2 domain.
#define QSCALE 0.06375871588055019f

typedef short s16x8 __attribute__((ext_vector_type(8)));
typedef float f32x4 __attribute__((ext_vector_type(4)));

typedef const __attribute__((address_space(1))) unsigned int ga_u32;
typedef __attribute__((address_space(3))) unsigned int lds_u32;

// async 16B global->LDS (dest = wave-uniform base + lane*16, linear)
__device__ __forceinline__ void gl_lds16(const unsigned short* g, unsigned short* l) {
    __builtin_amdgcn_global_load_lds((ga_u32*)g, (lds_u32*)l, 16, 0, 0);
}
__device__ __forceinline__ float exp2a(float x) {
    float r; asm("v_exp_f32 %0, %1" : "=v"(r) : "v"(x)); return r;
}
__device__ __forceinline__ unsigned int cvtpk(float lo, float hi) {
    unsigned int r; asm("v_cvt_pk_bf16_f32 %0, %1, %2" : "=v"(r) : "v"(lo), "v"(hi)); return r;
}
__device__ __forceinline__ unsigned short f2bf(float x) {
    unsigned int u = __builtin_bit_cast(unsigned int, x);
    u = (u + 0x7FFFu + ((u >> 16) & 1u)) >> 16;   // RNE
    return (unsigned short)u;
}
__device__ __forceinline__ float bflo(unsigned int w) {
    return __builtin_bit_cast(float, w << 16);
}
__device__ __forceinline__ float bfhi(unsigned int w) {
    return __builtin_bit_cast(float, w & 0xFFFF0000u);
}

// ---------------------------------------------------------------------------
// Kernel 0: split Wo (fp32 512x512) into bf16 hi + bf16 residual lo.
// Whi+Wlo represents Wo to ~2^-16 relative -> MFMA(A,Whi)+MFMA(A,Wlo) keeps
// fp32-level accuracy for the output projection.
// ---------------------------------------------------------------------------
__global__ __launch_bounds__(256) void wo_split_kernel(
    const float* __restrict__ Wo, unsigned short* __restrict__ Whi,
    unsigned short* __restrict__ Wlo)
{
    const int i = blockIdx.x * 256 + threadIdx.x;      // 0..65535, 4 elems each
    const float4 w = reinterpret_cast<const float4*>(Wo)[i];
    const unsigned int hxy = cvtpk(w.x, w.y);
    const unsigned int hzw = cvtpk(w.z, w.w);
    const unsigned int lxy = cvtpk(w.x - bflo(hxy), w.y - bfhi(hxy));
    const unsigned int lzw = cvtpk(w.z - bflo(hzw), w.w - bfhi(hzw));
    uint2 hh; hh.x = hxy; hh.y = hzw;
    uint2 ll; ll.x = lxy; ll.y = lzw;
    reinterpret_cast<uint2*>(Whi)[i] = hh;
    reinterpret_cast<uint2*>(Wlo)[i] = ll;
}

// ---------------------------------------------------------------------------
// Kernel 1: per-head QKV projection (fp32 compute, bf16 output).
// Q is pre-scaled by QSCALE (softmax scale folded + log2 domain).
// Qp/Kp: [nh][l][d]; Vt: [nh][d][l] (transposed for PV A-operand).
// ---------------------------------------------------------------------------
__global__ __launch_bounds__(256) void qkv_proj_kernel(
    const float* __restrict__ Q, const float* __restrict__ K, const float* __restrict__ V,
    const float* __restrict__ Wq, const float* __restrict__ Wk, const float* __restrict__ Wv,
    unsigned short* __restrict__ Qp, unsigned short* __restrict__ Kp,
    unsigned short* __restrict__ Vt)
{
    __shared__ float Xl[64][68];
    __shared__ float Wl[64][68];
    __shared__ __align__(16) unsigned short Yl[64][72];

    const int tid = threadIdx.x;
    const int lt = blockIdx.x;
    const int nh = blockIdx.y;
    const int m  = blockIdx.z;       // 0:Q 1:K 2:V
    const int n = nh >> 3, h = nh & 7;
    const int l0 = lt * 64;

    const float* __restrict__ in = (m == 0) ? Q : (m == 1) ? K : V;
    const float* __restrict__ W  = (m == 0) ? Wq : (m == 1) ? Wk : Wv;

#pragma unroll
    for (int it = 0; it < 4; ++it) {
        const int idx = tid + it * 256;
        const int r = idx >> 4, c4 = idx & 15;
        *reinterpret_cast<float4*>(&Xl[r][c4 * 4]) =
            *reinterpret_cast<const float4*>(in + (size_t)(n * L_ + l0 + r) * E_ + h * D_ + c4 * 4);
        *reinterpret_cast<float4*>(&Wl[r][c4 * 4]) =
            *reinterpret_cast<const float4*>(W + (size_t)r * D_ + c4 * 4);
    }
    __syncthreads();

    const int rp = tid & 31;
    const int eg = tid >> 5;
    float acc[2][8];
#pragma unroll
    for (int rr = 0; rr < 2; ++rr)
#pragma unroll
        for (int i = 0; i < 8; ++i) acc[rr][i] = 0.f;

#pragma unroll 4
    for (int d4 = 0; d4 < 16; ++d4) {
        const float4 xa = *reinterpret_cast<const float4*>(&Xl[rp][d4 * 4]);
        const float4 xb = *reinterpret_cast<const float4*>(&Xl[rp + 32][d4 * 4]);
#pragma unroll
        for (int i = 0; i < 8; ++i) {
            const float4 w = *reinterpret_cast<const float4*>(&Wl[eg * 8 + i][d4 * 4]);
            acc[0][i] += xa.x * w.x + xa.y * w.y + xa.z * w.z + xa.w * w.w;
            acc[1][i] += xb.x * w.x + xb.y * w.y + xb.z * w.z + xb.w * w.w;
        }
    }

    if (m == 0) {
#pragma unroll
        for (int rr = 0; rr < 2; ++rr)
#pragma unroll
            for (int i = 0; i < 8; ++i) acc[rr][i] *= QSCALE;
    }

    if (m < 2) {
        uint4 pa, pb;
        pa.x = cvtpk(acc[0][0], acc[0][1]); pa.y = cvtpk(acc[0][2], acc[0][3]);
        pa.z = cvtpk(acc[0][4], acc[0][5]); pa.w = cvtpk(acc[0][6], acc[0][7]);
        pb.x = cvtpk(acc[1][0], acc[1][1]); pb.y = cvtpk(acc[1][2], acc[1][3]);
        pb.z = cvtpk(acc[1][4], acc[1][5]); pb.w = cvtpk(acc[1][6], acc[1][7]);
        *reinterpret_cast<uint4*>(&Yl[rp][eg * 8]) = pa;
        *reinterpret_cast<uint4*>(&Yl[rp + 32][eg * 8]) = pb;
    } else {
#pragma unroll
        for (int i = 0; i < 8; ++i) {
            Yl[eg * 8 + i][rp] = f2bf(acc[0][i]);
            Yl[eg * 8 + i][rp + 32] = f2bf(acc[1][i]);
        }
    }
    __syncthreads();

    const int orow = tid >> 2;
    const int oc = (tid & 3) * 16;
    const uint4 v0 = *reinterpret_cast<const uint4*>(&Yl[orow][oc]);
    const uint4 v1 = *reinterpret_cast<const uint4*>(&Yl[orow][oc + 8]);
    unsigned short* dst;
    if (m == 0)      dst = Qp + ((size_t)nh * L_ + l0 + orow) * D_ + oc;
    else if (m == 1) dst = Kp + ((size_t)nh * L_ + l0 + orow) * D_ + oc;
    else             dst = Vt + ((size_t)nh * D_ + orow) * L_ + l0 + oc;
    *reinterpret_cast<uint4*>(dst) = v0;
    *reinterpret_cast<uint4*>(dst + 8) = v1;
}

// ---------------------------------------------------------------------------
// Kernel 2: bf16 MFMA flash attention, 2-phase double-buffered K/V staging via
// global_load_lds (linear LDS dest, inverse-swizzled per-lane SOURCE; swizzled
// ds_reads unchanged -> rule both-sides-or-neither holds).
// Scores arrive in log2 domain (Q pre-scaled); softmax = raw v_exp_f32.
// Defer-max (THR=8 in log2 units) skips O-rescale when max doesn't grow.
// Q-LDS reused as the P bounce buffer after fragment hoist (LDS = 40KB).
// XCD swizzle: 1024 blocks = 8 XCDs x 128 -> one XCD serves 4 heads' K/V.
// ---------------------------------------------------------------------------
__global__ __launch_bounds__(256) void attn_kernel(
    const unsigned short* __restrict__ Qp, const unsigned short* __restrict__ Kp,
    const unsigned short* __restrict__ Vt, unsigned short* __restrict__ AO)
{
    __shared__ __align__(16) unsigned short Qlds[4096];      // Q tile; later P (1KB/wave)
    __shared__ __align__(16) unsigned short Kdb[2][4096];
    __shared__ __align__(16) unsigned short Vdb[2][4096];

    const int tid = threadIdx.x;
    const int phys = blockIdx.x;
    const int bid = (phys & 7) * 128 + (phys >> 3);   // bijective: 1024 = 8*128
    const int qt = bid & 31;
    const int nh = bid >> 5;
    const int n = nh >> 3, h = nh & 7;
    const int q0 = qt * 64;
    const int wave = tid >> 6;
    const int lane = tid & 63;
    const int ql = lane & 15;
    const int g  = lane >> 4;

    const unsigned short* __restrict__ Qb = Qp + (size_t)nh * (L_ * D_);
    const unsigned short* __restrict__ Kb = Kp + (size_t)nh * (L_ * D_);
    const unsigned short* __restrict__ Vb = Vt + (size_t)nh * (D_ * L_);

    // staging geometry: granule G holds global element (row=G>>3, c8=(G&7)^(row&7))
    const int G0 = wave * 64 + lane;
    const int G1 = G0 + 256;
    const int r0 = G0 >> 3, c0 = (G0 & 7) ^ (r0 & 7);
    const int r1 = G1 >> 3, c1 = (G1 & 7) ^ (r1 & 7);

    // ---- stage Q tile ----
    gl_lds16(Qb + (size_t)(q0 + r0) * D_ + c0 * 8, Qlds + wave * 512);
    gl_lds16(Qb + (size_t)(q0 + r1) * D_ + c1 * 8, Qlds + 2048 + wave * 512);
    __syncthreads();

    const int qrow = wave * 16 + ql;
    s16x8 qfrag[2];
#pragma unroll
    for (int ks = 0; ks < 2; ++ks)
        qfrag[ks] = *reinterpret_cast<const s16x8*>(
            &Qlds[(qrow * 64 + ks * 32 + g * 8) ^ ((qrow & 7) << 3)]);

    // K/V staging base pointers (kt-invariant part)
    const unsigned short* ks0 = Kb + r0 * 64 + c0 * 8;
    const unsigned short* ks1 = Kb + r1 * 64 + c1 * 8;
    const unsigned short* vs0 = Vb + r0 * L_ + c0 * 8;
    const unsigned short* vs1 = Vb + r1 * L_ + c1 * 8;

    // prologue: stage kt=0 into buf 0
    gl_lds16(ks0, &Kdb[0][wave * 512]);
    gl_lds16(ks1, &Kdb[0][2048 + wave * 512]);
    gl_lds16(vs0, &Vdb[0][wave * 512]);
    gl_lds16(vs1, &Vdb[0][2048 + wave * 512]);

    unsigned short* __restrict__ Pl = Qlds + wave * 1024;

    float m_ = -INFINITY;
    float lsum = 0.f;
    f32x4 ot[4];
#pragma unroll
    for (int t = 0; t < 4; ++t) ot[t] = (f32x4){0.f, 0.f, 0.f, 0.f};

    for (int kt = 0; kt < L_ / 64; ++kt) {
        const int b = kt & 1;
        __syncthreads();   // own vmcnt(0) drained -> buf[b] ready for everyone
        if (kt + 1 < L_ / 64) {
            const int nb = b ^ 1;
            gl_lds16(ks0 + (kt + 1) * 4096, &Kdb[nb][wave * 512]);
            gl_lds16(ks1 + (kt + 1) * 4096, &Kdb[nb][2048 + wave * 512]);
            gl_lds16(vs0 + (kt + 1) * 64,   &Vdb[nb][wave * 512]);
            gl_lds16(vs1 + (kt + 1) * 64,   &Vdb[nb][2048 + wave * 512]);
        }
        const unsigned short* __restrict__ Kl = Kdb[b];
        const unsigned short* __restrict__ Vl = Vdb[b];

        // ---- St = K·Q^T (log2-domain scores) ----
        f32x4 st[4];
        __builtin_amdgcn_s_setprio(1);
#pragma unroll
        for (int kv = 0; kv < 4; ++kv) {
            st[kv] = (f32x4){0.f, 0.f, 0.f, 0.f};
            const int krow = kv * 16 + ql;
#pragma unroll
            for (int ks = 0; ks < 2; ++ks) {
                const s16x8 kf = *reinterpret_cast<const s16x8*>(
                    &Kl[(krow * 64 + ks * 32 + g * 8) ^ ((krow & 7) << 3)]);
                st[kv] = __builtin_amdgcn_mfma_f32_16x16x32_bf16(kf, qfrag[ks], st[kv], 0, 0, 0);
            }
        }
        __builtin_amdgcn_s_setprio(0);

        // ---- online softmax, base-2, defer-max ----
        float ps[16];
#pragma unroll
        for (int kv = 0; kv < 4; ++kv)
#pragma unroll
            for (int rr = 0; rr < 4; ++rr) ps[kv * 4 + rr] = st[kv][rr];

        float t0 = fmaxf(fmaxf(ps[0], ps[1]), ps[2]);
        float t1 = fmaxf(fmaxf(ps[3], ps[4]), ps[5]);
        float t2 = fmaxf(fmaxf(ps[6], ps[7]), ps[8]);
        float t3 = fmaxf(fmaxf(ps[9], ps[10]), ps[11]);
        float t4 = fmaxf(fmaxf(ps[12], ps[13]), ps[14]);
        float tmax = fmaxf(fmaxf(fmaxf(t0, t1), t2), fmaxf(fmaxf(t3, t4), ps[15]));
        tmax = fmaxf(tmax, __shfl_xor(tmax, 16));
        tmax = fmaxf(tmax, __shfl_xor(tmax, 32));

        if (!__all(tmax <= m_ + 8.f)) {       // first tile: m_=-inf -> taken
            const float newm = fmaxf(m_, tmax);
            const float corr = exp2a(m_ - newm);   // 0 on first tile
            lsum *= corr;
#pragma unroll
            for (int t = 0; t < 4; ++t) ot[t] *= corr;
            m_ = newm;
        }
        float tsum = 0.f;
#pragma unroll
        for (int i = 0; i < 16; ++i) {
            ps[i] = exp2a(ps[i] - m_);        // bounded by 2^8
            tsum += ps[i];
        }
        tsum += __shfl_xor(tsum, 16);
        tsum += __shfl_xor(tsum, 32);
        lsum += tsum;

        // ---- P (bf16) -> per-wave LDS, same-wave write->read ----
#pragma unroll
        for (int kv = 0; kv < 4; ++kv) {
            uint2 pw;
            pw.x = cvtpk(ps[kv * 4 + 0], ps[kv * 4 + 1]);
            pw.y = cvtpk(ps[kv * 4 + 2], ps[kv * 4 + 3]);
            *reinterpret_cast<uint2*>(
                &Pl[(ql * 64 + kv * 16 + g * 4) ^ ((ql & 7) << 3)]) = pw;
        }

        // ---- Ot += V^T·P^T ----
        s16x8 pf[2];
#pragma unroll
        for (int ks = 0; ks < 2; ++ks)
            pf[ks] = *reinterpret_cast<const s16x8*>(
                &Pl[(ql * 64 + ks * 32 + g * 8) ^ ((ql & 7) << 3)]);
        __builtin_amdgcn_s_setprio(1);
#pragma unroll
        for (int dt = 0; dt < 4; ++dt) {
            const int drow = dt * 16 + ql;
#pragma unroll
            for (int ks = 0; ks < 2; ++ks) {
                const s16x8 vf = *reinterpret_cast<const s16x8*>(
                    &Vl[(drow * 64 + ks * 32 + g * 8) ^ ((drow & 7) << 3)]);
                ot[dt] = __builtin_amdgcn_mfma_f32_16x16x32_bf16(vf, pf[ks], ot[dt], 0, 0, 0);
            }
        }
        __builtin_amdgcn_s_setprio(0);
    }

    // ---- epilogue ----
    const float inv = 1.f / lsum;
    const int lq = q0 + wave * 16 + ql;
#pragma unroll
    for (int dt = 0; dt < 4; ++dt) {
        uint2 o;
        o.x = cvtpk(ot[dt][0] * inv, ot[dt][1] * inv);
        o.y = cvtpk(ot[dt][2] * inv, ot[dt][3] * inv);
        const size_t elem = ((size_t)n * L_ + lq) * E_ + h * D_ + dt * 16 + g * 4;
        *reinterpret_cast<uint2*>(AO + elem) = o;
    }
}

// ---------------------------------------------------------------------------
// Kernel 3: output projection via bf16 MFMA with Wo = Whi + Wlo split.
// out[m][n] = sum_k AO[m][k]*(Whi+Wlo)[n][k] + bo[n].  M=8192,N=512,K=512.
// 64x64 tile per block, 4 waves x (16m x 64n), K in 8 steps of 64,
// double-buffered gl_lds staging (same inverse-swizzle scheme as attn).
// ---------------------------------------------------------------------------
__global__ __launch_bounds__(256) void out_proj_kernel(
    const unsigned short* __restrict__ AO, const unsigned short* __restrict__ Whi,
    const unsigned short* __restrict__ Wlo, const float* __restrict__ bo,
    float* __restrict__ out)
{
    __shared__ __align__(16) unsigned short Adb[2][4096];
    __shared__ __align__(16) unsigned short Hdb[2][4096];
    __shared__ __align__(16) unsigned short Ldb[2][4096];

    const int tid = threadIdx.x;
    const int bid = blockIdx.x;
    const int mt = bid >> 3, nt = bid & 7;
    const int m0 = mt * 64, n0 = nt * 64;
    const int wave = tid >> 6, lane = tid & 63;
    const int ql = lane & 15, g = lane >> 4;

    const int G0 = wave * 64 + lane;
    const int G1 = G0 + 256;
    const int r0 = G0 >> 3, c0 = (G0 & 7) ^ (r0 & 7);
    const int r1 = G1 >> 3, c1 = (G1 & 7) ^ (r1 & 7);

    const unsigned short* as0 = AO + (size_t)(m0 + r0) * E_ + c0 * 8;
    const unsigned short* as1 = AO + (size_t)(m0 + r1) * E_ + c1 * 8;
    const unsigned short* hs0 = Whi + (size_t)(n0 + r0) * E_ + c0 * 8;
    const unsigned short* hs1 = Whi + (size_t)(n0 + r1) * E_ + c1 * 8;
    const unsigned short* ls0 = Wlo + (size_t)(n0 + r0) * E_ + c0 * 8;
    const unsigned short* ls1 = Wlo + (size_t)(n0 + r1) * E_ + c1 * 8;

    gl_lds16(as0, &Adb[0][wave * 512]);
    gl_lds16(as1, &Adb[0][2048 + wave * 512]);
    gl_lds16(hs0, &Hdb[0][wave * 512]);
    gl_lds16(hs1, &Hdb[0][2048 + wave * 512]);
    gl_lds16(ls0, &Ldb[0][wave * 512]);
    gl_lds16(ls1, &Ldb[0][2048 + wave * 512]);

    float bias[4];
#pragma unroll
    for (int t = 0; t < 4; ++t) bias[t] = bo[n0 + t * 16 + ql];

    f32x4 acc[4];
#pragma unroll
    for (int t = 0; t < 4; ++t) acc[t] = (f32x4){0.f, 0.f, 0.f, 0.f};

    const int arow = wave * 16 + ql;

    for (int kc = 0; kc < 8; ++kc) {
        const int b = kc & 1;
        __syncthreads();
        if (kc + 1 < 8) {
            const int nb = b ^ 1;
            const int ko = (kc + 1) * 64;
            gl_lds16(as0 + ko, &Adb[nb][wave * 512]);
            gl_lds16(as1 + ko, &Adb[nb][2048 + wave * 512]);
            gl_lds16(hs0 + ko, &Hdb[nb][wave * 512]);
            gl_lds16(hs1 + ko, &Hdb[nb][2048 + wave * 512]);
            gl_lds16(ls0 + ko, &Ldb[nb][wave * 512]);
            gl_lds16(ls1 + ko, &Ldb[nb][2048 + wave * 512]);
        }
        const unsigned short* __restrict__ Al = Adb[b];
        const unsigned short* __restrict__ Hl = Hdb[b];
        const unsigned short* __restrict__ Ll = Ldb[b];

        s16x8 af[2];
#pragma unroll
        for (int ks = 0; ks < 2; ++ks)
            af[ks] = *reinterpret_cast<const s16x8*>(
                &Al[(arow * 64 + ks * 32 + g * 8) ^ ((arow & 7) << 3)]);

        __builtin_amdgcn_s_setprio(1);
#pragma unroll
        for (int t = 0; t < 4; ++t) {
            const int wrow = t * 16 + ql;
#pragma unroll
            for (int ks = 0; ks < 2; ++ks) {
                const s16x8 bh = *reinterpret_cast<const s16x8*>(
                    &Hl[(wrow * 64 + ks * 32 + g * 8) ^ ((wrow & 7) << 3)]);
                acc[t] = __builtin_amdgcn_mfma_f32_16x16x32_bf16(af[ks], bh, acc[t], 0, 0, 0);
                const s16x8 bl = *reinterpret_cast<const s16x8*>(
                    &Ll[(wrow * 64 + ks * 32 + g * 8) ^ ((wrow & 7) << 3)]);
                acc[t] = __builtin_amdgcn_mfma_f32_16x16x32_bf16(af[ks], bl, acc[t], 0, 0, 0);
            }
        }
        __builtin_amdgcn_s_setprio(0);
    }

    // epilogue: D[m = m0+wave*16+g*4+r][n = n0+t*16+ql]
#pragma unroll
    for (int t = 0; t < 4; ++t) {
#pragma unroll
        for (int r = 0; r < 4; ++r) {
            out[(size_t)(m0 + wave * 16 + g * 4 + r) * E_ + n0 + t * 16 + ql] =
                acc[t][r] + bias[t];
        }
    }
}

// ---------------------------------------------------------------------------
extern "C" void kernel_launch(void* const* d_in, const int* in_sizes, int n_in,
                              void* d_out, int out_size, void* d_ws, size_t ws_size,
                              hipStream_t stream)
{
    const float* Q  = (const float*)d_in[0];
    const float* K  = (const float*)d_in[1];
    const float* V  = (const float*)d_in[2];
    const float* Wq = (const float*)d_in[3];
    const float* Wk = (const float*)d_in[4];
    const float* Wv = (const float*)d_in[5];
    const float* Wo = (const float*)d_in[6];
    const float* bo = (const float*)d_in[7];
    float* out = (float*)d_out;

    unsigned short* ws = (unsigned short*)d_ws;
    const size_t SZ = (size_t)N_ * H_ * L_ * D_;   // 4,194,304 elems
    unsigned short* Qp  = ws;
    unsigned short* Kp  = ws + SZ;
    unsigned short* Vt  = ws + 2 * SZ;
    unsigned short* AO  = ws + 3 * SZ;
    unsigned short* Whi = ws + 4 * SZ;
    unsigned short* Wlo = ws + 4 * SZ + 262144;

    qkv_proj_kernel<<<dim3(32, 32, 3), 256, 0, stream>>>(Q, K, V, Wq, Wk, Wv, Qp, Kp, Vt);
    wo_split_kernel<<<256, 256, 0, stream>>>(Wo, Whi, Wlo);
    attn_kernel<<<N_ * H_ * (L_ / 64), 256, 0, stream>>>(Qp, Kp, Vt, AO);
    out_proj_kernel<<<(8192 / 64) * (E_ / 64), 256, 0, stream>>>(AO, Whi, Wlo, bo, out);
}

// Round 5
// 120.712 us; speedup vs baseline: 7.4389x; 1.0583x over previous
//
#include <hip/hip_runtime.h>
#include <math.h>

#define N_ 4
#define L_ 2048
#define E_ 512
#define H_ 8
#define D_ 64

// SCALE = 1/sqrt(512) (reference scales by sqrt(embed_size));
// QSCALE = SCALE * log2(e): scores come out of QK^T in log2 domain.
#define QSCALE 0.06375871588055019f

typedef short s16x8 __attribute__((ext_vector_type(8)));
typedef float f32x4 __attribute__((ext_vector_type(4)));
typedef float f32x16 __attribute__((ext_vector_type(16)));
typedef unsigned int u32x4 __attribute__((ext_vector_type(4)));

typedef const __attribute__((address_space(1))) unsigned int ga_u32;
typedef __attribute__((address_space(3))) unsigned int lds_u32;

// async 16B global->LDS (dest = wave-uniform base + lane*16, linear)
__device__ __forceinline__ void gl_lds16(const unsigned short* g, unsigned short* l) {
    __builtin_amdgcn_global_load_lds((ga_u32*)g, (lds_u32*)l, 16, 0, 0);
}
__device__ __forceinline__ float exp2a(float x) {
    float r; asm("v_exp_f32 %0, %1" : "=v"(r) : "v"(x)); return r;
}
__device__ __forceinline__ unsigned int cvtpk(float lo, float hi) {
    unsigned int r; asm("v_cvt_pk_bf16_f32 %0, %1, %2" : "=v"(r) : "v"(lo), "v"(hi)); return r;
}
// v_permlane32_swap_b32 a, b: a<-{a_lo, b_lo}, b<-{a_hi, b_hi} (lane halves)
__device__ __forceinline__ void swap32(unsigned int& a, unsigned int& b) {
    asm volatile("v_permlane32_swap_b32 %0, %1" : "+v"(a), "+v"(b));
}
__device__ __forceinline__ unsigned short f2bf(float x) {
    unsigned int u = __builtin_bit_cast(unsigned int, x);
    u = (u + 0x7FFFu + ((u >> 16) & 1u)) >> 16;   // RNE
    return (unsigned short)u;
}
__device__ __forceinline__ float bflo(unsigned int w) {
    return __builtin_bit_cast(float, w << 16);
}
__device__ __forceinline__ float bfhi(unsigned int w) {
    return __builtin_bit_cast(float, w & 0xFFFF0000u);
}

// ---------------------------------------------------------------------------
// Kernel 0: split Wo (fp32 512x512) into bf16 hi + bf16 residual lo.
// ---------------------------------------------------------------------------
__global__ __launch_bounds__(256) void wo_split_kernel(
    const float* __restrict__ Wo, unsigned short* __restrict__ Whi,
    unsigned short* __restrict__ Wlo)
{
    const int i = blockIdx.x * 256 + threadIdx.x;
    const float4 w = reinterpret_cast<const float4*>(Wo)[i];
    const unsigned int hxy = cvtpk(w.x, w.y);
    const unsigned int hzw = cvtpk(w.z, w.w);
    const unsigned int lxy = cvtpk(w.x - bflo(hxy), w.y - bfhi(hxy));
    const unsigned int lzw = cvtpk(w.z - bflo(hzw), w.w - bfhi(hzw));
    uint2 hh; hh.x = hxy; hh.y = hzw;
    uint2 ll; ll.x = lxy; ll.y = lzw;
    reinterpret_cast<uint2*>(Whi)[i] = hh;
    reinterpret_cast<uint2*>(Wlo)[i] = ll;
}

// ---------------------------------------------------------------------------
// Kernel 1: per-head QKV projection (fp32 compute, bf16 output).
// Q pre-scaled by QSCALE. Qp/Kp: [nh][l][d]; Vt: [nh][d][l].
// ---------------------------------------------------------------------------
__global__ __launch_bounds__(256) void qkv_proj_kernel(
    const float* __restrict__ Q, const float* __restrict__ K, const float* __restrict__ V,
    const float* __restrict__ Wq, const float* __restrict__ Wk, const float* __restrict__ Wv,
    unsigned short* __restrict__ Qp, unsigned short* __restrict__ Kp,
    unsigned short* __restrict__ Vt)
{
    __shared__ float Xl[64][68];
    __shared__ float Wl[64][68];
    __shared__ __align__(16) unsigned short Yl[64][72];

    const int tid = threadIdx.x;
    const int lt = blockIdx.x;
    const int nh = blockIdx.y;
    const int m  = blockIdx.z;       // 0:Q 1:K 2:V
    const int n = nh >> 3, h = nh & 7;
    const int l0 = lt * 64;

    const float* __restrict__ in = (m == 0) ? Q : (m == 1) ? K : V;
    const float* __restrict__ W  = (m == 0) ? Wq : (m == 1) ? Wk : Wv;

#pragma unroll
    for (int it = 0; it < 4; ++it) {
        const int idx = tid + it * 256;
        const int r = idx >> 4, c4 = idx & 15;
        *reinterpret_cast<float4*>(&Xl[r][c4 * 4]) =
            *reinterpret_cast<const float4*>(in + (size_t)(n * L_ + l0 + r) * E_ + h * D_ + c4 * 4);
        *reinterpret_cast<float4*>(&Wl[r][c4 * 4]) =
            *reinterpret_cast<const float4*>(W + (size_t)r * D_ + c4 * 4);
    }
    __syncthreads();

    const int rp = tid & 31;
    const int eg = tid >> 5;
    float acc[2][8];
#pragma unroll
    for (int rr = 0; rr < 2; ++rr)
#pragma unroll
        for (int i = 0; i < 8; ++i) acc[rr][i] = 0.f;

#pragma unroll 4
    for (int d4 = 0; d4 < 16; ++d4) {
        const float4 xa = *reinterpret_cast<const float4*>(&Xl[rp][d4 * 4]);
        const float4 xb = *reinterpret_cast<const float4*>(&Xl[rp + 32][d4 * 4]);
#pragma unroll
        for (int i = 0; i < 8; ++i) {
            const float4 w = *reinterpret_cast<const float4*>(&Wl[eg * 8 + i][d4 * 4]);
            acc[0][i] += xa.x * w.x + xa.y * w.y + xa.z * w.z + xa.w * w.w;
            acc[1][i] += xb.x * w.x + xb.y * w.y + xb.z * w.z + xb.w * w.w;
        }
    }

    if (m == 0) {
#pragma unroll
        for (int rr = 0; rr < 2; ++rr)
#pragma unroll
            for (int i = 0; i < 8; ++i) acc[rr][i] *= QSCALE;
    }

    if (m < 2) {
        uint4 pa, pb;
        pa.x = cvtpk(acc[0][0], acc[0][1]); pa.y = cvtpk(acc[0][2], acc[0][3]);
        pa.z = cvtpk(acc[0][4], acc[0][5]); pa.w = cvtpk(acc[0][6], acc[0][7]);
        pb.x = cvtpk(acc[1][0], acc[1][1]); pb.y = cvtpk(acc[1][2], acc[1][3]);
        pb.z = cvtpk(acc[1][4], acc[1][5]); pb.w = cvtpk(acc[1][6], acc[1][7]);
        *reinterpret_cast<uint4*>(&Yl[rp][eg * 8]) = pa;
        *reinterpret_cast<uint4*>(&Yl[rp + 32][eg * 8]) = pb;
    } else {
#pragma unroll
        for (int i = 0; i < 8; ++i) {
            Yl[eg * 8 + i][rp] = f2bf(acc[0][i]);
            Yl[eg * 8 + i][rp + 32] = f2bf(acc[1][i]);
        }
    }
    __syncthreads();

    const int orow = tid >> 2;
    const int oc = (tid & 3) * 16;
    const uint4 v0 = *reinterpret_cast<const uint4*>(&Yl[orow][oc]);
    const uint4 v1 = *reinterpret_cast<const uint4*>(&Yl[orow][oc + 8]);
    unsigned short* dst;
    if (m == 0)      dst = Qp + ((size_t)nh * L_ + l0 + orow) * D_ + oc;
    else if (m == 1) dst = Kp + ((size_t)nh * L_ + l0 + orow) * D_ + oc;
    else             dst = Vt + ((size_t)nh * D_ + orow) * L_ + l0 + oc;
    *reinterpret_cast<uint4*>(dst) = v0;
    *reinterpret_cast<uint4*>(dst + 8) = v1;
}

// ---------------------------------------------------------------------------
// Kernel 2: bf16 MFMA flash attention, 32x32x16 shape, P fully in-register.
// Block = 4 waves; each wave owns 32 q-rows (QBLK=128). KVBLK=64.
// S^T = K.Q^T via mfma_32x32x16: lane holds 32 scores of ONE q (col=lane&31;
// k = kv*32 + (reg&3) + 8*(reg>>2) + 4*(lane>>5)). Softmax reductions: one
// shfl_xor(32). P -> PV B-operand in registers: 16 cvt_pk + 8 permlane32_swap
// (swap(A0,A1) yields frag words w0/w2 for both lane halves; w1/w3 from B's).
// O^T += V^T.P^T. K/V double-buffered via gl_lds (inverse-swizzled source).
// Q loaded straight to registers (no Q LDS, no P LDS): LDS = 32KB.
// ---------------------------------------------------------------------------
__global__ __launch_bounds__(256) void attn_kernel(
    const unsigned short* __restrict__ Qp, const unsigned short* __restrict__ Kp,
    const unsigned short* __restrict__ Vt, unsigned short* __restrict__ AO)
{
    __shared__ __align__(16) unsigned short Kdb[2][4096];
    __shared__ __align__(16) unsigned short Vdb[2][4096];

    const int tid = threadIdx.x;
    const int phys = blockIdx.x;
    const int bid = (phys & 7) * 64 + (phys >> 3);   // bijective: 512 = 8*64
    const int qt = bid & 15;
    const int nh = bid >> 4;          // 4 heads per XCD -> K/V L2-resident
    const int n = nh >> 3, h = nh & 7;
    const int q0 = qt * 128;
    const int wave = tid >> 6;
    const int lane = tid & 63;
    const int l31 = lane & 31;
    const int hh  = lane >> 5;

    const unsigned short* __restrict__ Qb = Qp + (size_t)nh * (L_ * D_);
    const unsigned short* __restrict__ Kb = Kp + (size_t)nh * (L_ * D_);
    const unsigned short* __restrict__ Vb = Vt + (size_t)nh * (D_ * L_);

    // staging geometry: granule G -> global (row=G>>3, c8=(G&7)^(row&7))
    const int G0 = wave * 64 + lane;
    const int G1 = G0 + 256;
    const int r0 = G0 >> 3, c0 = (G0 & 7) ^ (r0 & 7);
    const int r1 = G1 >> 3, c1 = (G1 & 7) ^ (r1 & 7);

    const unsigned short* ks0 = Kb + r0 * 64 + c0 * 8;
    const unsigned short* ks1 = Kb + r1 * 64 + c1 * 8;
    const unsigned short* vs0 = Vb + r0 * L_ + c0 * 8;
    const unsigned short* vs1 = Vb + r1 * L_ + c1 * 8;

    // prologue: stage kt=0 into buf 0
    gl_lds16(ks0, &Kdb[0][wave * 512]);
    gl_lds16(ks1, &Kdb[0][2048 + wave * 512]);
    gl_lds16(vs0, &Vdb[0][wave * 512]);
    gl_lds16(vs1, &Vdb[0][2048 + wave * 512]);

    // Q fragments straight to registers: B[k=d][col=q], q=q0+wave*32+l31,
    // d = ks*16 + hh*8 + j
    const int qrow = q0 + wave * 32 + l31;
    s16x8 qfrag[4];
#pragma unroll
    for (int ks = 0; ks < 4; ++ks)
        qfrag[ks] = *reinterpret_cast<const s16x8*>(
            Qb + (size_t)qrow * D_ + ks * 16 + hh * 8);

    float m_ = -INFINITY;
    float lsum = 0.f;
    f32x16 ot[2];
    ot[0] = (f32x16)0.f;
    ot[1] = (f32x16)0.f;

    for (int kt = 0; kt < L_ / 64; ++kt) {
        const int b = kt & 1;
        __syncthreads();   // vmcnt(0) drained -> buf[b] ready for everyone
        if (kt + 1 < L_ / 64) {
            const int nb = b ^ 1;
            gl_lds16(ks0 + (kt + 1) * 4096, &Kdb[nb][wave * 512]);
            gl_lds16(ks1 + (kt + 1) * 4096, &Kdb[nb][2048 + wave * 512]);
            gl_lds16(vs0 + (kt + 1) * 64,   &Vdb[nb][wave * 512]);
            gl_lds16(vs1 + (kt + 1) * 64,   &Vdb[nb][2048 + wave * 512]);
        }
        const unsigned short* __restrict__ Kl = Kdb[b];
        const unsigned short* __restrict__ Vl = Vdb[b];

        // ---- S^T = K·Q^T (log2-domain scores) ----
        f32x16 st[2];
        __builtin_amdgcn_s_setprio(1);
#pragma unroll
        for (int kv = 0; kv < 2; ++kv) {
            st[kv] = (f32x16)0.f;
            const int krow = kv * 32 + l31;
#pragma unroll
            for (int ks = 0; ks < 4; ++ks) {
                const s16x8 kf = *reinterpret_cast<const s16x8*>(
                    &Kl[(krow * 64 + ks * 16 + hh * 8) ^ ((krow & 7) << 3)]);
                st[kv] = __builtin_amdgcn_mfma_f32_32x32x16_bf16(kf, qfrag[ks], st[kv], 0, 0, 0);
            }
        }
        __builtin_amdgcn_s_setprio(0);

        // ---- row max (32 values per lane, tree) + half-combine ----
        float mx[8];
#pragma unroll
        for (int r = 0; r < 4; ++r) {
            mx[r]     = fmaxf(fmaxf(st[0][4 * r], st[0][4 * r + 1]),
                              fmaxf(st[0][4 * r + 2], st[0][4 * r + 3]));
            mx[r + 4] = fmaxf(fmaxf(st[1][4 * r], st[1][4 * r + 1]),
                              fmaxf(st[1][4 * r + 2], st[1][4 * r + 3]));
        }
        float tmax = fmaxf(fmaxf(fmaxf(mx[0], mx[1]), fmaxf(mx[2], mx[3])),
                           fmaxf(fmaxf(mx[4], mx[5]), fmaxf(mx[6], mx[7])));
        tmax = fmaxf(tmax, __shfl_xor(tmax, 32));

        if (!__all(tmax <= m_ + 8.f)) {       // first tile: m_=-inf -> taken
            const float newm = fmaxf(m_, tmax);
            const float corr = exp2a(m_ - newm);   // 0 on first tile
            lsum *= corr;
            ot[0] *= corr;
            ot[1] *= corr;
            m_ = newm;
        }

        // ---- P = exp2(S - m) in regs; pack to PV B-frags (cvt_pk + swap) ----
        float tsum = 0.f;
        s16x8 pf[4];
#pragma unroll
        for (int kv = 0; kv < 2; ++kv) {
            float p[16];
#pragma unroll
            for (int i = 0; i < 16; ++i) {
                p[i] = exp2a(st[kv][i] - m_);   // bounded by 2^8
                tsum += p[i];
            }
            unsigned int A0 = cvtpk(p[0],  p[1]),  B0 = cvtpk(p[2],  p[3]);
            unsigned int A1 = cvtpk(p[4],  p[5]),  B1 = cvtpk(p[6],  p[7]);
            unsigned int A2 = cvtpk(p[8],  p[9]),  B2 = cvtpk(p[10], p[11]);
            unsigned int A3 = cvtpk(p[12], p[13]), B3 = cvtpk(p[14], p[15]);
            swap32(A0, A1); swap32(B0, B1);   // -> frag words w0/w2 (k chunk lo)
            swap32(A2, A3); swap32(B2, B3);   // -> frag words for k chunk hi
            u32x4 lo; lo[0] = A0; lo[1] = B0; lo[2] = A1; lo[3] = B1;
            u32x4 hi; hi[0] = A2; hi[1] = B2; hi[2] = A3; hi[3] = B3;
            pf[kv * 2 + 0] = __builtin_bit_cast(s16x8, lo);
            pf[kv * 2 + 1] = __builtin_bit_cast(s16x8, hi);
        }
        tsum += __shfl_xor(tsum, 32);
        lsum += tsum;

        // ---- O^T += V^T·P^T ----
        __builtin_amdgcn_s_setprio(1);
#pragma unroll
        for (int dt = 0; dt < 2; ++dt) {
            const int drow = dt * 32 + l31;
#pragma unroll
            for (int kc = 0; kc < 4; ++kc) {
                const s16x8 vf = *reinterpret_cast<const s16x8*>(
                    &Vl[(drow * 64 + kc * 16 + hh * 8) ^ ((drow & 7) << 3)]);
                ot[dt] = __builtin_amdgcn_mfma_f32_32x32x16_bf16(vf, pf[kc], ot[dt], 0, 0, 0);
            }
        }
        __builtin_amdgcn_s_setprio(0);
    }

    // ---- epilogue: lane holds O^T[d][q=qrow]; d = dt*32 + 8r + 4hh + (0..3) ----
    const float inv = 1.f / lsum;
#pragma unroll
    for (int dt = 0; dt < 2; ++dt) {
#pragma unroll
        for (int r = 0; r < 4; ++r) {
            uint2 o;
            o.x = cvtpk(ot[dt][4 * r + 0] * inv, ot[dt][4 * r + 1] * inv);
            o.y = cvtpk(ot[dt][4 * r + 2] * inv, ot[dt][4 * r + 3] * inv);
            const size_t elem = ((size_t)n * L_ + qrow) * E_ + h * D_ + dt * 32 + r * 8 + hh * 4;
            *reinterpret_cast<uint2*>(AO + elem) = o;
        }
    }
}

// ---------------------------------------------------------------------------
// Kernel 3: output projection via bf16 MFMA with Wo = Whi + Wlo split.
// ---------------------------------------------------------------------------
__global__ __launch_bounds__(256) void out_proj_kernel(
    const unsigned short* __restrict__ AO, const unsigned short* __restrict__ Whi,
    const unsigned short* __restrict__ Wlo, const float* __restrict__ bo,
    float* __restrict__ out)
{
    __shared__ __align__(16) unsigned short Adb[2][4096];
    __shared__ __align__(16) unsigned short Hdb[2][4096];
    __shared__ __align__(16) unsigned short Ldb[2][4096];

    const int tid = threadIdx.x;
    const int bid = blockIdx.x;
    const int mt = bid >> 3, nt = bid & 7;
    const int m0 = mt * 64, n0 = nt * 64;
    const int wave = tid >> 6, lane = tid & 63;
    const int ql = lane & 15, g = lane >> 4;

    const int G0 = wave * 64 + lane;
    const int G1 = G0 + 256;
    const int r0 = G0 >> 3, c0 = (G0 & 7) ^ (r0 & 7);
    const int r1 = G1 >> 3, c1 = (G1 & 7) ^ (r1 & 7);

    const unsigned short* as0 = AO + (size_t)(m0 + r0) * E_ + c0 * 8;
    const unsigned short* as1 = AO + (size_t)(m0 + r1) * E_ + c1 * 8;
    const unsigned short* hs0 = Whi + (size_t)(n0 + r0) * E_ + c0 * 8;
    const unsigned short* hs1 = Whi + (size_t)(n0 + r1) * E_ + c1 * 8;
    const unsigned short* ls0 = Wlo + (size_t)(n0 + r0) * E_ + c0 * 8;
    const unsigned short* ls1 = Wlo + (size_t)(n0 + r1) * E_ + c1 * 8;

    gl_lds16(as0, &Adb[0][wave * 512]);
    gl_lds16(as1, &Adb[0][2048 + wave * 512]);
    gl_lds16(hs0, &Hdb[0][wave * 512]);
    gl_lds16(hs1, &Hdb[0][2048 + wave * 512]);
    gl_lds16(ls0, &Ldb[0][wave * 512]);
    gl_lds16(ls1, &Ldb[0][2048 + wave * 512]);

    float bias[4];
#pragma unroll
    for (int t = 0; t < 4; ++t) bias[t] = bo[n0 + t * 16 + ql];

    f32x4 acc[4];
#pragma unroll
    for (int t = 0; t < 4; ++t) acc[t] = (f32x4){0.f, 0.f, 0.f, 0.f};

    const int arow = wave * 16 + ql;

    for (int kc = 0; kc < 8; ++kc) {
        const int b = kc & 1;
        __syncthreads();
        if (kc + 1 < 8) {
            const int nb = b ^ 1;
            const int ko = (kc + 1) * 64;
            gl_lds16(as0 + ko, &Adb[nb][wave * 512]);
            gl_lds16(as1 + ko, &Adb[nb][2048 + wave * 512]);
            gl_lds16(hs0 + ko, &Hdb[nb][wave * 512]);
            gl_lds16(hs1 + ko, &Hdb[nb][2048 + wave * 512]);
            gl_lds16(ls0 + ko, &Ldb[nb][wave * 512]);
            gl_lds16(ls1 + ko, &Ldb[nb][2048 + wave * 512]);
        }
        const unsigned short* __restrict__ Al = Adb[b];
        const unsigned short* __restrict__ Hl = Hdb[b];
        const unsigned short* __restrict__ Ll = Ldb[b];

        s16x8 af[2];
#pragma unroll
        for (int ks = 0; ks < 2; ++ks)
            af[ks] = *reinterpret_cast<const s16x8*>(
                &Al[(arow * 64 + ks * 32 + g * 8) ^ ((arow & 7) << 3)]);

        __builtin_amdgcn_s_setprio(1);
#pragma unroll
        for (int t = 0; t < 4; ++t) {
            const int wrow = t * 16 + ql;
#pragma unroll
            for (int ks = 0; ks < 2; ++ks) {
                const s16x8 bh = *reinterpret_cast<const s16x8*>(
                    &Hl[(wrow * 64 + ks * 32 + g * 8) ^ ((wrow & 7) << 3)]);
                acc[t] = __builtin_amdgcn_mfma_f32_16x16x32_bf16(af[ks], bh, acc[t], 0, 0, 0);
                const s16x8 bl = *reinterpret_cast<const s16x8*>(
                    &Ll[(wrow * 64 + ks * 32 + g * 8) ^ ((wrow & 7) << 3)]);
                acc[t] = __builtin_amdgcn_mfma_f32_16x16x32_bf16(af[ks], bl, acc[t], 0, 0, 0);
            }
        }
        __builtin_amdgcn_s_setprio(0);
    }

    // epilogue: D[m = m0+wave*16+g*4+r][n = n0+t*16+ql]
#pragma unroll
    for (int t = 0; t < 4; ++t) {
#pragma unroll
        for (int r = 0; r < 4; ++r) {
            out[(size_t)(m0 + wave * 16 + g * 4 + r) * E_ + n0 + t * 16 + ql] =
                acc[t][r] + bias[t];
        }
    }
}

// ---------------------------------------------------------------------------
extern "C" void kernel_launch(void* const* d_in, const int* in_sizes, int n_in,
                              void* d_out, int out_size, void* d_ws, size_t ws_size,
                              hipStream_t stream)
{
    const float* Q  = (const float*)d_in[0];
    const float* K  = (const float*)d_in[1];
    const float* V  = (const float*)d_in[2];
    const float* Wq = (const float*)d_in[3];
    const float* Wk = (const float*)d_in[4];
    const float* Wv = (const float*)d_in[5];
    const float* Wo = (const float*)d_in[6];
    const float* bo = (const float*)d_in[7];
    float* out = (float*)d_out;

    unsigned short* ws = (unsigned short*)d_ws;
    const size_t SZ = (size_t)N_ * H_ * L_ * D_;   // 4,194,304 elems
    unsigned short* Qp  = ws;
    unsigned short* Kp  = ws + SZ;
    unsigned short* Vt  = ws + 2 * SZ;
    unsigned short* AO  = ws + 3 * SZ;
    unsigned short* Whi = ws + 4 * SZ;
    unsigned short* Wlo = ws + 4 * SZ + 262144;

    qkv_proj_kernel<<<dim3(32, 32, 3), 256, 0, stream>>>(Q, K, V, Wq, Wk, Wv, Qp, Kp, Vt);
    wo_split_kernel<<<256, 256, 0, stream>>>(Wo, Whi, Wlo);
    attn_kernel<<<512, 256, 0, stream>>>(Qp, Kp, Vt, AO);
    out_proj_kernel<<<(8192 / 64) * (E_ / 64), 256, 0, stream>>>(AO, Whi, Wlo, bo, out);
}

// Round 6
// 114.322 us; speedup vs baseline: 7.8546x; 1.0559x over previous
//
#include <hip/hip_runtime.h>
#include <math.h>

#define N_ 4
#define L_ 2048
#define E_ 512
#define H_ 8
#define D_ 64

// SCALE = 1/sqrt(512) (reference scales by sqrt(embed_size));
// QSCALE = SCALE * log2(e): scores come out of QK^T in log2 domain.
#define QSCALE 0.06375871588055019f

typedef short s16x8 __attribute__((ext_vector_type(8)));
typedef float f32x4 __attribute__((ext_vector_type(4)));
typedef float f32x16 __attribute__((ext_vector_type(16)));
typedef unsigned int u32x4 __attribute__((ext_vector_type(4)));

typedef const __attribute__((address_space(1))) unsigned int ga_u32;
typedef __attribute__((address_space(3))) unsigned int lds_u32;

// async 16B global->LDS (dest = wave-uniform base + lane*16, linear)
__device__ __forceinline__ void gl_lds16(const unsigned short* g, unsigned short* l) {
    __builtin_amdgcn_global_load_lds((ga_u32*)g, (lds_u32*)l, 16, 0, 0);
}
__device__ __forceinline__ float exp2a(float x) {
    float r; asm("v_exp_f32 %0, %1" : "=v"(r) : "v"(x)); return r;
}
__device__ __forceinline__ unsigned int cvtpk(float lo, float hi) {
    unsigned int r; asm("v_cvt_pk_bf16_f32 %0, %1, %2" : "=v"(r) : "v"(lo), "v"(hi)); return r;
}
// v_permlane32_swap_b32 a, b: a<-{a_lo, b_lo}, b<-{a_hi, b_hi} (lane halves)
__device__ __forceinline__ void swap32(unsigned int& a, unsigned int& b) {
    asm volatile("v_permlane32_swap_b32 %0, %1" : "+v"(a), "+v"(b));
}
__device__ __forceinline__ float max3f(float a, float b, float c) {
    return fmaxf(fmaxf(a, b), c);   // clang fuses to v_max3_f32
}
__device__ __forceinline__ unsigned short f2bf(float x) {
    unsigned int u = __builtin_bit_cast(unsigned int, x);
    u = (u + 0x7FFFu + ((u >> 16) & 1u)) >> 16;   // RNE
    return (unsigned short)u;
}
__device__ __forceinline__ float bflo(unsigned int w) {
    return __builtin_bit_cast(float, w << 16);
}
__device__ __forceinline__ float bfhi(unsigned int w) {
    return __builtin_bit_cast(float, w & 0xFFFF0000u);
}

// ---------------------------------------------------------------------------
// Kernel 0: split Wo (fp32 512x512) into bf16 hi + bf16 residual lo.
// ---------------------------------------------------------------------------
__global__ __launch_bounds__(256) void wo_split_kernel(
    const float* __restrict__ Wo, unsigned short* __restrict__ Whi,
    unsigned short* __restrict__ Wlo)
{
    const int i = blockIdx.x * 256 + threadIdx.x;
    const float4 w = reinterpret_cast<const float4*>(Wo)[i];
    const unsigned int hxy = cvtpk(w.x, w.y);
    const unsigned int hzw = cvtpk(w.z, w.w);
    const unsigned int lxy = cvtpk(w.x - bflo(hxy), w.y - bfhi(hxy));
    const unsigned int lzw = cvtpk(w.z - bflo(hzw), w.w - bfhi(hzw));
    uint2 hh; hh.x = hxy; hh.y = hzw;
    uint2 ll; ll.x = lxy; ll.y = lzw;
    reinterpret_cast<uint2*>(Whi)[i] = hh;
    reinterpret_cast<uint2*>(Wlo)[i] = ll;
}

// ---------------------------------------------------------------------------
// Kernel 1: per-head QKV projection (fp32 compute, bf16 output).
// Q pre-scaled by QSCALE. Qp/Kp: [nh][l][d]; Vt: [nh][d][l].
// ---------------------------------------------------------------------------
__global__ __launch_bounds__(256) void qkv_proj_kernel(
    const float* __restrict__ Q, const float* __restrict__ K, const float* __restrict__ V,
    const float* __restrict__ Wq, const float* __restrict__ Wk, const float* __restrict__ Wv,
    unsigned short* __restrict__ Qp, unsigned short* __restrict__ Kp,
    unsigned short* __restrict__ Vt)
{
    __shared__ float Xl[64][68];
    __shared__ float Wl[64][68];
    __shared__ __align__(16) unsigned short Yl[64][72];

    const int tid = threadIdx.x;
    const int lt = blockIdx.x;
    const int nh = blockIdx.y;
    const int m  = blockIdx.z;       // 0:Q 1:K 2:V
    const int n = nh >> 3, h = nh & 7;
    const int l0 = lt * 64;

    const float* __restrict__ in = (m == 0) ? Q : (m == 1) ? K : V;
    const float* __restrict__ W  = (m == 0) ? Wq : (m == 1) ? Wk : Wv;

#pragma unroll
    for (int it = 0; it < 4; ++it) {
        const int idx = tid + it * 256;
        const int r = idx >> 4, c4 = idx & 15;
        *reinterpret_cast<float4*>(&Xl[r][c4 * 4]) =
            *reinterpret_cast<const float4*>(in + (size_t)(n * L_ + l0 + r) * E_ + h * D_ + c4 * 4);
        *reinterpret_cast<float4*>(&Wl[r][c4 * 4]) =
            *reinterpret_cast<const float4*>(W + (size_t)r * D_ + c4 * 4);
    }
    __syncthreads();

    const int rp = tid & 31;
    const int eg = tid >> 5;
    float acc[2][8];
#pragma unroll
    for (int rr = 0; rr < 2; ++rr)
#pragma unroll
        for (int i = 0; i < 8; ++i) acc[rr][i] = 0.f;

#pragma unroll 4
    for (int d4 = 0; d4 < 16; ++d4) {
        const float4 xa = *reinterpret_cast<const float4*>(&Xl[rp][d4 * 4]);
        const float4 xb = *reinterpret_cast<const float4*>(&Xl[rp + 32][d4 * 4]);
#pragma unroll
        for (int i = 0; i < 8; ++i) {
            const float4 w = *reinterpret_cast<const float4*>(&Wl[eg * 8 + i][d4 * 4]);
            acc[0][i] += xa.x * w.x + xa.y * w.y + xa.z * w.z + xa.w * w.w;
            acc[1][i] += xb.x * w.x + xb.y * w.y + xb.z * w.z + xb.w * w.w;
        }
    }

    if (m == 0) {
#pragma unroll
        for (int rr = 0; rr < 2; ++rr)
#pragma unroll
            for (int i = 0; i < 8; ++i) acc[rr][i] *= QSCALE;
    }

    if (m < 2) {
        uint4 pa, pb;
        pa.x = cvtpk(acc[0][0], acc[0][1]); pa.y = cvtpk(acc[0][2], acc[0][3]);
        pa.z = cvtpk(acc[0][4], acc[0][5]); pa.w = cvtpk(acc[0][6], acc[0][7]);
        pb.x = cvtpk(acc[1][0], acc[1][1]); pb.y = cvtpk(acc[1][2], acc[1][3]);
        pb.z = cvtpk(acc[1][4], acc[1][5]); pb.w = cvtpk(acc[1][6], acc[1][7]);
        *reinterpret_cast<uint4*>(&Yl[rp][eg * 8]) = pa;
        *reinterpret_cast<uint4*>(&Yl[rp + 32][eg * 8]) = pb;
    } else {
#pragma unroll
        for (int i = 0; i < 8; ++i) {
            Yl[eg * 8 + i][rp] = f2bf(acc[0][i]);
            Yl[eg * 8 + i][rp + 32] = f2bf(acc[1][i]);
        }
    }
    __syncthreads();

    const int orow = tid >> 2;
    const int oc = (tid & 3) * 16;
    const uint4 v0 = *reinterpret_cast<const uint4*>(&Yl[orow][oc]);
    const uint4 v1 = *reinterpret_cast<const uint4*>(&Yl[orow][oc + 8]);
    unsigned short* dst;
    if (m == 0)      dst = Qp + ((size_t)nh * L_ + l0 + orow) * D_ + oc;
    else if (m == 1) dst = Kp + ((size_t)nh * L_ + l0 + orow) * D_ + oc;
    else             dst = Vt + ((size_t)nh * D_ + orow) * L_ + l0 + oc;
    *reinterpret_cast<uint4*>(dst) = v0;
    *reinterpret_cast<uint4*>(dst + 8) = v1;
}

// ---------------------------------------------------------------------------
// Kernel 2: bf16 MFMA flash attention, 32x32x16, P in-register, software-
// pipelined: per iter t -> [QK(t) mfma] [PV(t-1) mfma + ones-mfma lsum]
// [softmax(t) -> pf].  V triple-buffered (PV reads t-1 while t+1 stages),
// K double-buffered.  lsum accumulated by MFMA with a ones A-operand
// (B-frag == P), so softmax has no dependent add chain and no sum shfl.
// Rescale (defer-max THR=8) is applied AFTER PV(t-1) -> pf/ot consistent.
// ---------------------------------------------------------------------------
__global__ __launch_bounds__(256) void attn_kernel(
    const unsigned short* __restrict__ Qp, const unsigned short* __restrict__ Kp,
    const unsigned short* __restrict__ Vt, unsigned short* __restrict__ AO)
{
    __shared__ __align__(16) unsigned short Kdb[2][4096];
    __shared__ __align__(16) unsigned short Vdb[3][4096];

    const int tid = threadIdx.x;
    const int phys = blockIdx.x;
    const int bid = (phys & 7) * 64 + (phys >> 3);   // bijective: 512 = 8*64
    const int qt = bid & 15;
    const int nh = bid >> 4;          // 4 heads per XCD -> K/V L2-resident
    const int n = nh >> 3, h = nh & 7;
    const int q0 = qt * 128;
    const int wave = tid >> 6;
    const int lane = tid & 63;
    const int l31 = lane & 31;
    const int hh  = lane >> 5;

    const unsigned short* __restrict__ Qb = Qp + (size_t)nh * (L_ * D_);
    const unsigned short* __restrict__ Kb = Kp + (size_t)nh * (L_ * D_);
    const unsigned short* __restrict__ Vb = Vt + (size_t)nh * (D_ * L_);

    // staging geometry: granule G -> global (row=G>>3, c8=(G&7)^(row&7))
    const int G0 = wave * 64 + lane;
    const int G1 = G0 + 256;
    const int r0 = G0 >> 3, c0 = (G0 & 7) ^ (r0 & 7);
    const int r1 = G1 >> 3, c1 = (G1 & 7) ^ (r1 & 7);

    const unsigned short* ks0 = Kb + r0 * 64 + c0 * 8;
    const unsigned short* ks1 = Kb + r1 * 64 + c1 * 8;
    const unsigned short* vs0 = Vb + r0 * L_ + c0 * 8;
    const unsigned short* vs1 = Vb + r1 * L_ + c1 * 8;

    // prologue: stage kt=0
    gl_lds16(ks0, &Kdb[0][wave * 512]);
    gl_lds16(ks1, &Kdb[0][2048 + wave * 512]);
    gl_lds16(vs0, &Vdb[0][wave * 512]);
    gl_lds16(vs1, &Vdb[0][2048 + wave * 512]);

    // Q fragments straight to registers: B[k=d][col=q], q=q0+wave*32+l31
    const int qrow = q0 + wave * 32 + l31;
    s16x8 qfrag[4];
#pragma unroll
    for (int ks = 0; ks < 4; ++ks)
        qfrag[ks] = *reinterpret_cast<const s16x8*>(
            Qb + (size_t)qrow * D_ + ks * 16 + hh * 8);

    // ones A-fragment for the lsum MFMA
    s16x8 onesf;
#pragma unroll
    for (int i = 0; i < 8; ++i) onesf[i] = (short)0x3F80;

    float m_ = -INFINITY;
    f32x16 lsacc = (f32x16)0.f;      // per-q key-sum accumulator (all 16 equal)
    f32x16 ot[2];
    ot[0] = (f32x16)0.f;
    ot[1] = (f32x16)0.f;
    s16x8 pf[4];                      // P frags of tile t-1, live across iters

    // V ring: vcur = V(t), vprev = V(t-1), vnext = stage target V(t+1)
    unsigned short* vprev = Vdb[2];
    unsigned short* vcur  = Vdb[0];
    unsigned short* vnext = Vdb[1];

    for (int kt = 0; kt < L_ / 64; ++kt) {
        __syncthreads();   // stage(kt) landed everywhere; old buffers free
        if (kt + 1 < L_ / 64) {
            unsigned short* kn = Kdb[(kt + 1) & 1];
            gl_lds16(ks0 + (kt + 1) * 4096, kn + wave * 512);
            gl_lds16(ks1 + (kt + 1) * 4096, kn + 2048 + wave * 512);
            gl_lds16(vs0 + (kt + 1) * 64,   vnext + wave * 512);
            gl_lds16(vs1 + (kt + 1) * 64,   vnext + 2048 + wave * 512);
        }
        const unsigned short* __restrict__ Kl = Kdb[kt & 1];

        // ---- QK(t): S^T = K·Q^T (log2-domain scores) ----
        f32x16 st[2];
        __builtin_amdgcn_s_setprio(1);
#pragma unroll
        for (int kv = 0; kv < 2; ++kv) {
            st[kv] = (f32x16)0.f;
            const int krow = kv * 32 + l31;
#pragma unroll
            for (int ks = 0; ks < 4; ++ks) {
                const s16x8 kf = *reinterpret_cast<const s16x8*>(
                    &Kl[(krow * 64 + ks * 16 + hh * 8) ^ ((krow & 7) << 3)]);
                st[kv] = __builtin_amdgcn_mfma_f32_32x32x16_bf16(kf, qfrag[ks], st[kv], 0, 0, 0);
            }
        }

        // ---- PV(t-1) + ones-mfma lsum (in flight during softmax(t)) ----
        if (kt) {
#pragma unroll
            for (int dt = 0; dt < 2; ++dt) {
                const int drow = dt * 32 + l31;
#pragma unroll
                for (int kc = 0; kc < 4; ++kc) {
                    const s16x8 vf = *reinterpret_cast<const s16x8*>(
                        &vprev[(drow * 64 + kc * 16 + hh * 8) ^ ((drow & 7) << 3)]);
                    ot[dt] = __builtin_amdgcn_mfma_f32_32x32x16_bf16(vf, pf[kc], ot[dt], 0, 0, 0);
                }
            }
#pragma unroll
            for (int kc = 0; kc < 4; ++kc)
                lsacc = __builtin_amdgcn_mfma_f32_32x32x16_bf16(onesf, pf[kc], lsacc, 0, 0, 0);
        }
        __builtin_amdgcn_s_setprio(0);

        // ---- softmax(t): max3 tree + defer-max rescale + exp + pack ----
        const float t0 = max3f(st[0][0],  st[0][1],  st[0][2]);
        const float t1 = max3f(st[0][3],  st[0][4],  st[0][5]);
        const float t2 = max3f(st[0][6],  st[0][7],  st[0][8]);
        const float t3 = max3f(st[0][9],  st[0][10], st[0][11]);
        const float t4 = max3f(st[0][12], st[0][13], st[0][14]);
        const float t5 = max3f(st[0][15], st[1][0],  st[1][1]);
        const float t6 = max3f(st[1][2],  st[1][3],  st[1][4]);
        const float t7 = max3f(st[1][5],  st[1][6],  st[1][7]);
        const float t8 = max3f(st[1][8],  st[1][9],  st[1][10]);
        const float t9 = max3f(st[1][11], st[1][12], st[1][13]);
        const float ta = fmaxf(st[1][14], st[1][15]);
        const float u0 = max3f(t0, t1, t2);
        const float u1 = max3f(t3, t4, t5);
        const float u2 = max3f(t6, t7, t8);
        const float u3 = fmaxf(t9, ta);
        float tmax = fmaxf(max3f(u0, u1, u2), u3);
        tmax = fmaxf(tmax, __shfl_xor(tmax, 32));

        if (!__all(tmax <= m_ + 8.f)) {       // first tile: m_=-inf -> taken
            const float newm = fmaxf(m_, tmax);
            const float corr = exp2a(m_ - newm);   // 0 on first tile
            lsacc *= corr;
            ot[0] *= corr;
            ot[1] *= corr;
            m_ = newm;
        }

#pragma unroll
        for (int kv = 0; kv < 2; ++kv) {
            float p[16];
#pragma unroll
            for (int i = 0; i < 16; ++i) p[i] = exp2a(st[kv][i] - m_);  // <= 2^8
            unsigned int A0 = cvtpk(p[0],  p[1]),  B0 = cvtpk(p[2],  p[3]);
            unsigned int A1 = cvtpk(p[4],  p[5]),  B1 = cvtpk(p[6],  p[7]);
            unsigned int A2 = cvtpk(p[8],  p[9]),  B2 = cvtpk(p[10], p[11]);
            unsigned int A3 = cvtpk(p[12], p[13]), B3 = cvtpk(p[14], p[15]);
            swap32(A0, A1); swap32(B0, B1);
            swap32(A2, A3); swap32(B2, B3);
            u32x4 lo; lo[0] = A0; lo[1] = B0; lo[2] = A1; lo[3] = B1;
            u32x4 hi; hi[0] = A2; hi[1] = B2; hi[2] = A3; hi[3] = B3;
            pf[kv * 2 + 0] = __builtin_bit_cast(s16x8, lo);
            pf[kv * 2 + 1] = __builtin_bit_cast(s16x8, hi);
        }

        // rotate V ring
        unsigned short* tmp = vprev;
        vprev = vcur; vcur = vnext; vnext = tmp;
    }

    // ---- epilogue: final PV + lsum, then write AO ----
    __builtin_amdgcn_s_setprio(1);
#pragma unroll
    for (int dt = 0; dt < 2; ++dt) {
        const int drow = dt * 32 + l31;
#pragma unroll
        for (int kc = 0; kc < 4; ++kc) {
            const s16x8 vf = *reinterpret_cast<const s16x8*>(
                &vprev[(drow * 64 + kc * 16 + hh * 8) ^ ((drow & 7) << 3)]);
            ot[dt] = __builtin_amdgcn_mfma_f32_32x32x16_bf16(vf, pf[kc], ot[dt], 0, 0, 0);
        }
    }
#pragma unroll
    for (int kc = 0; kc < 4; ++kc)
        lsacc = __builtin_amdgcn_mfma_f32_32x32x16_bf16(onesf, pf[kc], lsacc, 0, 0, 0);
    __builtin_amdgcn_s_setprio(0);

    const float inv = 1.f / lsacc[0];     // ones-mfma sums ALL keys (both halves)
#pragma unroll
    for (int dt = 0; dt < 2; ++dt) {
#pragma unroll
        for (int r = 0; r < 4; ++r) {
            uint2 o;
            o.x = cvtpk(ot[dt][4 * r + 0] * inv, ot[dt][4 * r + 1] * inv);
            o.y = cvtpk(ot[dt][4 * r + 2] * inv, ot[dt][4 * r + 3] * inv);
            const size_t elem = ((size_t)n * L_ + qrow) * E_ + h * D_ + dt * 32 + r * 8 + hh * 4;
            *reinterpret_cast<uint2*>(AO + elem) = o;
        }
    }
}

// ---------------------------------------------------------------------------
// Kernel 3: output projection via bf16 MFMA with Wo = Whi + Wlo split.
// ---------------------------------------------------------------------------
__global__ __launch_bounds__(256) void out_proj_kernel(
    const unsigned short* __restrict__ AO, const unsigned short* __restrict__ Whi,
    const unsigned short* __restrict__ Wlo, const float* __restrict__ bo,
    float* __restrict__ out)
{
    __shared__ __align__(16) unsigned short Adb[2][4096];
    __shared__ __align__(16) unsigned short Hdb[2][4096];
    __shared__ __align__(16) unsigned short Ldb[2][4096];

    const int tid = threadIdx.x;
    const int bid = blockIdx.x;
    const int mt = bid >> 3, nt = bid & 7;
    const int m0 = mt * 64, n0 = nt * 64;
    const int wave = tid >> 6, lane = tid & 63;
    const int ql = lane & 15, g = lane >> 4;

    const int G0 = wave * 64 + lane;
    const int G1 = G0 + 256;
    const int r0 = G0 >> 3, c0 = (G0 & 7) ^ (r0 & 7);
    const int r1 = G1 >> 3, c1 = (G1 & 7) ^ (r1 & 7);

    const unsigned short* as0 = AO + (size_t)(m0 + r0) * E_ + c0 * 8;
    const unsigned short* as1 = AO + (size_t)(m0 + r1) * E_ + c1 * 8;
    const unsigned short* hs0 = Whi + (size_t)(n0 + r0) * E_ + c0 * 8;
    const unsigned short* hs1 = Whi + (size_t)(n0 + r1) * E_ + c1 * 8;
    const unsigned short* ls0 = Wlo + (size_t)(n0 + r0) * E_ + c0 * 8;
    const unsigned short* ls1 = Wlo + (size_t)(n0 + r1) * E_ + c1 * 8;

    gl_lds16(as0, &Adb[0][wave * 512]);
    gl_lds16(as1, &Adb[0][2048 + wave * 512]);
    gl_lds16(hs0, &Hdb[0][wave * 512]);
    gl_lds16(hs1, &Hdb[0][2048 + wave * 512]);
    gl_lds16(ls0, &Ldb[0][wave * 512]);
    gl_lds16(ls1, &Ldb[0][2048 + wave * 512]);

    float bias[4];
#pragma unroll
    for (int t = 0; t < 4; ++t) bias[t] = bo[n0 + t * 16 + ql];

    f32x4 acc[4];
#pragma unroll
    for (int t = 0; t < 4; ++t) acc[t] = (f32x4){0.f, 0.f, 0.f, 0.f};

    const int arow = wave * 16 + ql;

    for (int kc = 0; kc < 8; ++kc) {
        const int b = kc & 1;
        __syncthreads();
        if (kc + 1 < 8) {
            const int nb = b ^ 1;
            const int ko = (kc + 1) * 64;
            gl_lds16(as0 + ko, &Adb[nb][wave * 512]);
            gl_lds16(as1 + ko, &Adb[nb][2048 + wave * 512]);
            gl_lds16(hs0 + ko, &Hdb[nb][wave * 512]);
            gl_lds16(hs1 + ko, &Hdb[nb][2048 + wave * 512]);
            gl_lds16(ls0 + ko, &Ldb[nb][wave * 512]);
            gl_lds16(ls1 + ko, &Ldb[nb][2048 + wave * 512]);
        }
        const unsigned short* __restrict__ Al = Adb[b];
        const unsigned short* __restrict__ Hl = Hdb[b];
        const unsigned short* __restrict__ Ll = Ldb[b];

        s16x8 af[2];
#pragma unroll
        for (int ks = 0; ks < 2; ++ks)
            af[ks] = *reinterpret_cast<const s16x8*>(
                &Al[(arow * 64 + ks * 32 + g * 8) ^ ((arow & 7) << 3)]);

        __builtin_amdgcn_s_setprio(1);
#pragma unroll
        for (int t = 0; t < 4; ++t) {
            const int wrow = t * 16 + ql;
#pragma unroll
            for (int ks = 0; ks < 2; ++ks) {
                const s16x8 bh = *reinterpret_cast<const s16x8*>(
                    &Hl[(wrow * 64 + ks * 32 + g * 8) ^ ((wrow & 7) << 3)]);
                acc[t] = __builtin_amdgcn_mfma_f32_16x16x32_bf16(af[ks], bh, acc[t], 0, 0, 0);
                const s16x8 bl = *reinterpret_cast<const s16x8*>(
                    &Ll[(wrow * 64 + ks * 32 + g * 8) ^ ((wrow & 7) << 3)]);
                acc[t] = __builtin_amdgcn_mfma_f32_16x16x32_bf16(af[ks], bl, acc[t], 0, 0, 0);
            }
        }
        __builtin_amdgcn_s_setprio(0);
    }

    // epilogue: D[m = m0+wave*16+g*4+r][n = n0+t*16+ql]
#pragma unroll
    for (int t = 0; t < 4; ++t) {
#pragma unroll
        for (int r = 0; r < 4; ++r) {
            out[(size_t)(m0 + wave * 16 + g * 4 + r) * E_ + n0 + t * 16 + ql] =
                acc[t][r] + bias[t];
        }
    }
}

// ---------------------------------------------------------------------------
extern "C" void kernel_launch(void* const* d_in, const int* in_sizes, int n_in,
                              void* d_out, int out_size, void* d_ws, size_t ws_size,
                              hipStream_t stream)
{
    const float* Q  = (const float*)d_in[0];
    const float* K  = (const float*)d_in[1];
    const float* V  = (const float*)d_in[2];
    const float* Wq = (const float*)d_in[3];
    const float* Wk = (const float*)d_in[4];
    const float* Wv = (const float*)d_in[5];
    const float* Wo = (const float*)d_in[6];
    const float* bo = (const float*)d_in[7];
    float* out = (float*)d_out;

    unsigned short* ws = (unsigned short*)d_ws;
    const size_t SZ = (size_t)N_ * H_ * L_ * D_;   // 4,194,304 elems
    unsigned short* Qp  = ws;
    unsigned short* Kp  = ws + SZ;
    unsigned short* Vt  = ws + 2 * SZ;
    unsigned short* AO  = ws + 3 * SZ;
    unsigned short* Whi = ws + 4 * SZ;
    unsigned short* Wlo = ws + 4 * SZ + 262144;

    qkv_proj_kernel<<<dim3(32, 32, 3), 256, 0, stream>>>(Q, K, V, Wq, Wk, Wv, Qp, Kp, Vt);
    wo_split_kernel<<<256, 256, 0, stream>>>(Wo, Whi, Wlo);
    attn_kernel<<<512, 256, 0, stream>>>(Qp, Kp, Vt, AO);
    out_proj_kernel<<<(8192 / 64) * (E_ / 64), 256, 0, stream>>>(AO, Whi, Wlo, bo, out);
}